// Round 1
// baseline (7933.502 us; speedup 1.0000x reference)
//
#include <hip/hip_runtime.h>

#define NIMG 16
#define IN_CH 512
#define OUT_CH 256
#define HIN 64
#define HOUT 128

#define OGB 8   // output channels per block
#define CB 8    // input-channel chunk staged in LDS
#define QT 16   // quads per tile side (32x32 output pixels)

#define WSCALE 0.014731391f      // 1/sqrt(9*512)
#define ACT_GAIN 1.41421356237f  // sqrt(2)
#define CLAMP_V 256.0f

// Parity tap matrices: G[p][i][a] = u[a-1+2i-p], u = {1,3,3,1}/4 (0 if OOR)
__device__ __constant__ float c_G[2][3][3] = {
    {{0.00f, 0.25f, 0.75f}, {0.75f, 0.75f, 0.25f}, {0.25f, 0.00f, 0.00f}},
    {{0.00f, 0.00f, 0.25f}, {0.25f, 0.75f, 0.75f}, {0.75f, 0.25f, 0.00f}}
};

// E[o][c][i*3+j][pu*2+pv] = WSCALE * sum_{a,b} w[o][c][a][b] G[pu][i][a] G[pv][j][b]
__global__ void build_e_kernel(const float* __restrict__ w, float* __restrict__ e_ws) {
    int gid = blockIdx.x * blockDim.x + threadIdx.x;
    if (gid >= OUT_CH * IN_CH) return;
    float wm[3][3];
    const float* wp = w + (size_t)gid * 9;
#pragma unroll
    for (int a = 0; a < 3; ++a)
#pragma unroll
        for (int b = 0; b < 3; ++b)
            wm[a][b] = wp[a * 3 + b] * WSCALE;
    float* op = e_ws + (size_t)gid * 36;
#pragma unroll
    for (int i = 0; i < 3; ++i)
#pragma unroll
        for (int j = 0; j < 3; ++j)
#pragma unroll
            for (int pu = 0; pu < 2; ++pu)
#pragma unroll
                for (int pv = 0; pv < 2; ++pv) {
                    float s = 0.f;
#pragma unroll
                    for (int a = 0; a < 3; ++a)
#pragma unroll
                        for (int b = 0; b < 3; ++b)
                            s += wm[a][b] * c_G[pu][i][a] * c_G[pv][j][b];
                    op[(i * 3 + j) * 4 + pu * 2 + pv] = s;
                }
}

// Fused: 3x3 parity conv over x + bias + leaky-relu*sqrt2 + clamp.
// Block: one n, OGB output channels, QTxQT quads (2 output pixels per quad side).
// Thread: 2 horizontally adjacent quads x 4 channels x 4 parities = 32 acc.
__global__ __launch_bounds__(256) void fused_conv_kernel(
    const float* __restrict__ x, const float* __restrict__ e_ws,
    const float* __restrict__ bias, float* __restrict__ out)
{
    __shared__ float sX[CB][18][19];      // padded stride 19 vs bank conflicts
    __shared__ float4 sE[OGB * CB * 9];   // [ol][cc][ij] float4 over parity

    const int tid = threadIdx.x;
    const int o2 = tid >> 7;         // 0..1: which 4-channel subgroup
    const int qy = (tid >> 3) & 15;  // quad row 0..15
    const int qxp = tid & 7;         // quad-pair col 0..7

    const int tileIdx = blockIdx.x;          // 0..15
    const int hq0 = (tileIdx >> 2) * QT;
    const int wq0 = (tileIdx & 3) * QT;
    const int o0 = blockIdx.y * OGB;
    const int n = blockIdx.z;

    float4 acc[2][4];
#pragma unroll
    for (int q = 0; q < 2; ++q)
#pragma unroll
        for (int oo = 0; oo < 4; ++oo)
            acc[q][oo] = make_float4(0.f, 0.f, 0.f, 0.f);

    for (int c0 = 0; c0 < IN_CH; c0 += CB) {
        // ---- stage x tile (zero-fill halo at image borders) ----
        for (int idx = tid; idx < CB * 18 * 18; idx += 256) {
            int cc = idx / 324;
            int rem = idx - cc * 324;
            int r = rem / 18;
            int col = rem - r * 18;
            int h = hq0 - 1 + r;
            int ww = wq0 - 1 + col;
            float v = 0.f;
            if (h >= 0 && h < HIN && ww >= 0 && ww < HIN)
                v = x[(((size_t)n * IN_CH + (c0 + cc)) * HIN + h) * HIN + ww];
            sX[cc][r][col] = v;
        }
        // ---- stage E (contiguous per output channel) ----
        {
            float* sEf = (float*)sE;
            for (int idx = tid; idx < OGB * CB * 36; idx += 256) {
                int ol = idx / (CB * 36);
                int rem = idx - ol * (CB * 36);
                sEf[ol * (CB * 36) + rem] =
                    e_ws[((size_t)(o0 + ol) * IN_CH + c0) * 36 + rem];
            }
        }
        __syncthreads();

#pragma unroll 1
        for (int cc = 0; cc < CB; ++cc) {
#pragma unroll
            for (int i = 0; i < 3; ++i) {
#pragma unroll
                for (int j = 0; j < 3; ++j) {
                    float xv0 = sX[cc][qy + i][2 * qxp + j];
                    float xv1 = sX[cc][qy + i][2 * qxp + 1 + j];
#pragma unroll
                    for (int oo = 0; oo < 4; ++oo) {
                        float4 e = sE[((o2 * 4 + oo) * CB + cc) * 9 + i * 3 + j];
                        acc[0][oo].x += xv0 * e.x;
                        acc[0][oo].y += xv0 * e.y;
                        acc[0][oo].z += xv0 * e.z;
                        acc[0][oo].w += xv0 * e.w;
                        acc[1][oo].x += xv1 * e.x;
                        acc[1][oo].y += xv1 * e.y;
                        acc[1][oo].z += xv1 * e.z;
                        acc[1][oo].w += xv1 * e.w;
                    }
                }
            }
        }
        __syncthreads();
    }

    // ---- epilogue: bias, leaky relu * sqrt(2), clamp ----
#pragma unroll
    for (int q = 0; q < 2; ++q) {
        int qx = 2 * qxp + q;
        int u0 = 2 * (hq0 + qy);
        int v0 = 2 * (wq0 + qx);
#pragma unroll
        for (int oo = 0; oo < 4; ++oo) {
            int o = o0 + o2 * 4 + oo;
            float b = bias[o];
            float vals[4] = {acc[q][oo].x, acc[q][oo].y, acc[q][oo].z, acc[q][oo].w};
#pragma unroll
            for (int p = 0; p < 4; ++p) {
                int pu = p >> 1, pv = p & 1;
                float v = vals[p] + b;
                v = (v >= 0.f ? v : 0.2f * v) * ACT_GAIN;
                v = fminf(fmaxf(v, -CLAMP_V), CLAMP_V);
                out[(((size_t)n * OUT_CH + o) * HOUT + (u0 + pu)) * HOUT + (v0 + pv)] = v;
            }
        }
    }
}

extern "C" void kernel_launch(void* const* d_in, const int* in_sizes, int n_in,
                              void* d_out, int out_size, void* d_ws, size_t ws_size,
                              hipStream_t stream) {
    const float* x = (const float*)d_in[0];
    const float* w = (const float*)d_in[1];
    const float* bias = (const float*)d_in[2];
    float* out = (float*)d_out;
    float* e_ws = (float*)d_ws;  // 256*512*36*4 = 18.9 MB

    build_e_kernel<<<(OUT_CH * IN_CH + 255) / 256, 256, 0, stream>>>(w, e_ws);
    dim3 grid(16, OUT_CH / OGB, NIMG);
    fused_conv_kernel<<<grid, 256, 0, stream>>>(x, e_ws, bias, out);
}

// Round 2
// 795.479 us; speedup vs baseline: 9.9732x; 9.9732x over previous
//
#include <hip/hip_runtime.h>
#include <hip/hip_bf16.h>

#define NIMG 16
#define IN_CH 512
#define OUT_CH 256
#define HIN 64
#define HOUT 128
#define HP 66  // padded spatial (1-pixel zero halo)

#define WSCALE 0.014731391f      // 1/sqrt(9*512)
#define ACT_GAIN 1.41421356237f  // sqrt(2)
#define CLAMP_V 256.0f

typedef __attribute__((ext_vector_type(8))) short bf16x8;
typedef __attribute__((ext_vector_type(4))) float f32x4;

// Parity tap matrices: G[p][i][a] = u[a-1+2i-p], u = {1,3,3,1}/4 (0 if OOR)
__device__ __constant__ float c_G[2][3][3] = {
    {{0.00f, 0.25f, 0.75f}, {0.75f, 0.75f, 0.25f}, {0.25f, 0.00f, 0.00f}},
    {{0.00f, 0.00f, 0.25f}, {0.25f, 0.75f, 0.75f}, {0.75f, 0.25f, 0.00f}}
};

#define XBF_BYTES ((size_t)NIMG * HP * HP * IN_CH * 2)     // 71,368,704
#define EBF_BYTES ((size_t)9 * 1024 * IN_CH * 2)           //  9,437,184
#define WS_NEED (XBF_BYTES + EBF_BYTES)

// ---------------- x -> padded NHWC bf16 [16][66][66][512] ----------------
__global__ __launch_bounds__(256) void xpose_kernel(const float* __restrict__ x,
                                                    __hip_bfloat16* __restrict__ xbf) {
    const int n = blockIdx.z;
    const int hp = blockIdx.y;        // 0..65
    const int c0 = blockIdx.x << 6;   // 8 chunks of 64 channels
    const int tid = threadIdx.x;
    const size_t obase = ((size_t)n * HP + hp) * HP;  // pixel-row base

    if (hp == 0 || hp == HP - 1) {
        for (int idx = tid; idx < HP * 64; idx += 256) {
            int wp = idx >> 6, c = idx & 63;
            xbf[(obase + wp) * IN_CH + c0 + c] = __float2bfloat16(0.f);
        }
        return;
    }
    __shared__ float tile[64][65];
    {
        int cc = tid >> 6, w = tid & 63;
        for (int cb = 0; cb < 64; cb += 4)
            tile[cb + cc][w] =
                x[(((size_t)n * IN_CH + c0 + cb + cc) * HIN + (hp - 1)) * HIN + w];
    }
    __syncthreads();
    {
        int c = tid & 63, wg = tid >> 6;
        for (int wb = 0; wb < 64; wb += 4) {
            int w2 = wb + wg;
            xbf[(obase + (w2 + 1)) * IN_CH + c0 + c] = __float2bfloat16(tile[c][w2]);
        }
        if (tid < 128) {
            int which = tid >> 6, c2 = tid & 63;
            xbf[(obase + (which ? (HP - 1) : 0)) * IN_CH + c0 + c2] = __float2bfloat16(0.f);
        }
    }
}

// ---------------- w -> E bf16 [9(tap)][1024(oc*4+par)][512(c)] ----------------
__global__ __launch_bounds__(256) void build_ebf_kernel(const float* __restrict__ w,
                                                        __hip_bfloat16* __restrict__ ebf) {
    int gid = blockIdx.x * 256 + threadIdx.x;  // oc*512 + c
    if (gid >= OUT_CH * IN_CH) return;
    int oc = gid >> 9, c = gid & 511;
    float wm[3][3];
    const float* wp = w + (size_t)gid * 9;
#pragma unroll
    for (int a = 0; a < 3; ++a)
#pragma unroll
        for (int b = 0; b < 3; ++b) wm[a][b] = wp[a * 3 + b] * WSCALE;
#pragma unroll
    for (int i = 0; i < 3; ++i)
#pragma unroll
        for (int j = 0; j < 3; ++j)
#pragma unroll
            for (int pu = 0; pu < 2; ++pu)
#pragma unroll
                for (int pv = 0; pv < 2; ++pv) {
                    float s = 0.f;
#pragma unroll
                    for (int a = 0; a < 3; ++a)
#pragma unroll
                        for (int b = 0; b < 3; ++b)
                            s += wm[a][b] * c_G[pu][i][a] * c_G[pv][j][b];
                    ebf[((size_t)(i * 3 + j) * 1024 + oc * 4 + pu * 2 + pv) * IN_CH + c] =
                        __float2bfloat16(s);
                }
}

// ---------------- implicit-GEMM MFMA conv ----------------
// M = 65536 quads (tile 128 = 16 qr x 8 qc), N = 1024 (oc*4+par, tile 128), K = 9*512
__global__ __launch_bounds__(256) void mfma_conv_kernel(
    const __hip_bfloat16* __restrict__ xbf, const __hip_bfloat16* __restrict__ ebf,
    const float* __restrict__ bias, float* __restrict__ out) {
    __shared__ __align__(16) __hip_bfloat16 As[128 * 64];
    __shared__ __align__(16) __hip_bfloat16 Bs[128 * 64];

    const int tid = threadIdx.x;
    const int lane = tid & 63;
    const int wid = tid >> 6;
    const int wy = wid >> 1, wx = wid & 1;   // 2x2 wave grid, 64x64 C each
    const int lm = lane & 15, lk = lane >> 4;
    const int sq = lane >> 3, soct = lane & 7;  // staging: row-in-group, 16B oct

    const int n = blockIdx.x >> 5;
    const int t = blockIdx.x & 31;
    const int qh0 = (t >> 3) << 4;  // 0..48
    const int qw0 = (t & 7) << 3;   // 0..56
    const int n0 = blockIdx.y << 7;

    static const int FI[9] = {0, 0, 0, 1, 1, 1, 2, 2, 2};
    static const int FJ[9] = {0, 1, 2, 0, 1, 2, 0, 1, 2};

    f32x4 acc[4][4];
#pragma unroll
    for (int mi = 0; mi < 4; ++mi)
#pragma unroll
        for (int ni = 0; ni < 4; ++ni) acc[mi][ni] = (f32x4)(0.f);

#pragma unroll 1
    for (int ij = 0; ij < 9; ++ij) {
        const int fi = FI[ij], fj = FJ[ij];
#pragma unroll 1
        for (int c0 = 0; c0 < IN_CH; c0 += 64) {
            __syncthreads();
            // ---- stage A[128 quads][64 c], swizzled source, linear LDS dest ----
#pragma unroll
            for (int it = 0; it < 4; ++it) {
                int q = it * 32 + wid * 8 + sq;
                int qr = q >> 3, qc = q & 7;
                int hp = qh0 + fi + qr;  // padded coords, always in-bounds
                int wp = qw0 + fj + qc;
                const __hip_bfloat16* src = xbf +
                    (((size_t)n * HP + hp) * HP + wp) * IN_CH + c0 + ((soct ^ (q & 7)) << 3);
                __builtin_amdgcn_global_load_lds(
                    (const __attribute__((address_space(1))) unsigned int*)src,
                    (__attribute__((address_space(3))) unsigned int*)&As[(it * 32 + wid * 8) * 64],
                    16, 0, 0);
            }
            // ---- stage B[128 n][64 c] from E ----
#pragma unroll
            for (int it = 0; it < 4; ++it) {
                int r = it * 32 + wid * 8 + sq;
                const __hip_bfloat16* src = ebf +
                    ((size_t)ij * 1024 + n0 + r) * IN_CH + c0 + ((soct ^ (r & 7)) << 3);
                __builtin_amdgcn_global_load_lds(
                    (const __attribute__((address_space(1))) unsigned int*)src,
                    (__attribute__((address_space(3))) unsigned int*)&Bs[(it * 32 + wid * 8) * 64],
                    16, 0, 0);
            }
            __syncthreads();
            // ---- compute: 2 k-chunks x 16 MFMA ----
#pragma unroll
            for (int kc = 0; kc < 2; ++kc) {
                bf16x8 af[4], bfr[4];
                const int colb = (kc * 4 + lk) << 3;
#pragma unroll
                for (int mi = 0; mi < 4; ++mi) {
                    int m = wy * 64 + mi * 16 + lm;
                    af[mi] = *(const bf16x8*)&As[m * 64 + (colb ^ ((m & 7) << 3))];
                }
#pragma unroll
                for (int ni = 0; ni < 4; ++ni) {
                    int r = wx * 64 + ni * 16 + lm;
                    bfr[ni] = *(const bf16x8*)&Bs[r * 64 + (colb ^ ((r & 7) << 3))];
                }
#pragma unroll
                for (int mi = 0; mi < 4; ++mi)
#pragma unroll
                    for (int ni = 0; ni < 4; ++ni)
                        acc[mi][ni] = __builtin_amdgcn_mfma_f32_16x16x32_bf16(
                            af[mi], bfr[ni], acc[mi][ni], 0, 0, 0);
            }
        }
    }

    // ---- epilogue: bias + leaky-relu*sqrt2 + clamp, scatter to NCHW ----
#pragma unroll
    for (int mi = 0; mi < 4; ++mi) {
#pragma unroll
        for (int v = 0; v < 4; ++v) {
            int m = wy * 64 + mi * 16 + lk * 4 + v;
            int qr = m >> 3, qc = m & 7;
            int hb = 2 * (qh0 + qr), wb = 2 * (qw0 + qc);
#pragma unroll
            for (int ni = 0; ni < 4; ++ni) {
                int nn = n0 + wx * 64 + ni * 16 + lm;
                int oc = nn >> 2, pu = (nn >> 1) & 1, pv = nn & 1;
                float val = acc[mi][ni][v] + bias[oc];
                val = (val >= 0.f ? val : 0.2f * val) * ACT_GAIN;
                val = fminf(fmaxf(val, -CLAMP_V), CLAMP_V);
                out[(((size_t)n * OUT_CH + oc) * HOUT + (hb + pu)) * HOUT + (wb + pv)] = val;
            }
        }
    }
}

// ---------------- fallback (R1 proven path) if workspace too small ----------------
__global__ void build_e_kernel(const float* __restrict__ w, float* __restrict__ e_ws) {
    int gid = blockIdx.x * blockDim.x + threadIdx.x;
    if (gid >= OUT_CH * IN_CH) return;
    float wm[3][3];
    const float* wp = w + (size_t)gid * 9;
#pragma unroll
    for (int a = 0; a < 3; ++a)
#pragma unroll
        for (int b = 0; b < 3; ++b) wm[a][b] = wp[a * 3 + b] * WSCALE;
    float* op = e_ws + (size_t)gid * 36;
#pragma unroll
    for (int i = 0; i < 3; ++i)
#pragma unroll
        for (int j = 0; j < 3; ++j)
#pragma unroll
            for (int pu = 0; pu < 2; ++pu)
#pragma unroll
                for (int pv = 0; pv < 2; ++pv) {
                    float s = 0.f;
#pragma unroll
                    for (int a = 0; a < 3; ++a)
#pragma unroll
                        for (int b = 0; b < 3; ++b)
                            s += wm[a][b] * c_G[pu][i][a] * c_G[pv][j][b];
                    op[(i * 3 + j) * 4 + pu * 2 + pv] = s;
                }
}

#define OGB 8
#define CB 8
#define QT 16
__global__ __launch_bounds__(256) void fused_conv_kernel(
    const float* __restrict__ x, const float* __restrict__ e_ws,
    const float* __restrict__ bias, float* __restrict__ out) {
    __shared__ float sX[CB][18][19];
    __shared__ float4 sE[OGB * CB * 9];
    const int tid = threadIdx.x;
    const int o2 = tid >> 7;
    const int qy = (tid >> 3) & 15;
    const int qxp = tid & 7;
    const int tileIdx = blockIdx.x;
    const int hq0 = (tileIdx >> 2) * QT;
    const int wq0 = (tileIdx & 3) * QT;
    const int o0 = blockIdx.y * OGB;
    const int n = blockIdx.z;
    float4 acc[2][4];
#pragma unroll
    for (int q = 0; q < 2; ++q)
#pragma unroll
        for (int oo = 0; oo < 4; ++oo) acc[q][oo] = make_float4(0.f, 0.f, 0.f, 0.f);
    for (int c0 = 0; c0 < IN_CH; c0 += CB) {
        for (int idx = tid; idx < CB * 18 * 18; idx += 256) {
            int cc = idx / 324;
            int rem = idx - cc * 324;
            int r = rem / 18;
            int col = rem - r * 18;
            int h = hq0 - 1 + r;
            int ww = wq0 - 1 + col;
            float v = 0.f;
            if (h >= 0 && h < HIN && ww >= 0 && ww < HIN)
                v = x[(((size_t)n * IN_CH + (c0 + cc)) * HIN + h) * HIN + ww];
            sX[cc][r][col] = v;
        }
        {
            float* sEf = (float*)sE;
            for (int idx = tid; idx < OGB * CB * 36; idx += 256) {
                int ol = idx / (CB * 36);
                int rem = idx - ol * (CB * 36);
                sEf[ol * (CB * 36) + rem] =
                    e_ws[((size_t)(o0 + ol) * IN_CH + c0) * 36 + rem];
            }
        }
        __syncthreads();
#pragma unroll 1
        for (int cc = 0; cc < CB; ++cc) {
#pragma unroll
            for (int i = 0; i < 3; ++i) {
#pragma unroll
                for (int j = 0; j < 3; ++j) {
                    float xv0 = sX[cc][qy + i][2 * qxp + j];
                    float xv1 = sX[cc][qy + i][2 * qxp + 1 + j];
#pragma unroll
                    for (int oo = 0; oo < 4; ++oo) {
                        float4 e = sE[((o2 * 4 + oo) * CB + cc) * 9 + i * 3 + j];
                        acc[0][oo].x += xv0 * e.x; acc[0][oo].y += xv0 * e.y;
                        acc[0][oo].z += xv0 * e.z; acc[0][oo].w += xv0 * e.w;
                        acc[1][oo].x += xv1 * e.x; acc[1][oo].y += xv1 * e.y;
                        acc[1][oo].z += xv1 * e.z; acc[1][oo].w += xv1 * e.w;
                    }
                }
            }
        }
        __syncthreads();
    }
#pragma unroll
    for (int q = 0; q < 2; ++q) {
        int qx = 2 * qxp + q;
        int u0 = 2 * (hq0 + qy);
        int v0 = 2 * (wq0 + qx);
#pragma unroll
        for (int oo = 0; oo < 4; ++oo) {
            int o = o0 + o2 * 4 + oo;
            float b = bias[o];
            float vals[4] = {acc[q][oo].x, acc[q][oo].y, acc[q][oo].z, acc[q][oo].w};
#pragma unroll
            for (int p = 0; p < 4; ++p) {
                int pu = p >> 1, pv = p & 1;
                float v = vals[p] + b;
                v = (v >= 0.f ? v : 0.2f * v) * ACT_GAIN;
                v = fminf(fmaxf(v, -CLAMP_V), CLAMP_V);
                out[(((size_t)n * OUT_CH + o) * HOUT + (u0 + pu)) * HOUT + (v0 + pv)] = v;
            }
        }
    }
}

extern "C" void kernel_launch(void* const* d_in, const int* in_sizes, int n_in,
                              void* d_out, int out_size, void* d_ws, size_t ws_size,
                              hipStream_t stream) {
    const float* x = (const float*)d_in[0];
    const float* w = (const float*)d_in[1];
    const float* bias = (const float*)d_in[2];
    float* out = (float*)d_out;

    if (ws_size >= WS_NEED) {
        __hip_bfloat16* xbf = (__hip_bfloat16*)d_ws;
        __hip_bfloat16* ebf = (__hip_bfloat16*)((char*)d_ws + XBF_BYTES);
        xpose_kernel<<<dim3(8, HP, NIMG), 256, 0, stream>>>(x, xbf);
        build_ebf_kernel<<<(OUT_CH * IN_CH + 255) / 256, 256, 0, stream>>>(w, ebf);
        mfma_conv_kernel<<<dim3(512, 8), 256, 0, stream>>>(xbf, ebf, bias, out);
    } else {
        float* e_ws = (float*)d_ws;
        build_e_kernel<<<(OUT_CH * IN_CH + 255) / 256, 256, 0, stream>>>(w, e_ws);
        dim3 grid(16, OUT_CH / OGB, NIMG);
        fused_conv_kernel<<<grid, 256, 0, stream>>>(x, e_ws, bias, out);
    }
}

// Round 3
// 705.421 us; speedup vs baseline: 11.2465x; 1.1277x over previous
//
#include <hip/hip_runtime.h>
#include <hip/hip_bf16.h>

#define NIMG 16
#define IN_CH 512
#define OUT_CH 256
#define HIN 64
#define HOUT 128
#define HP 66  // padded spatial (1-pixel zero halo)

#define WSCALE 0.014731391f      // 1/sqrt(9*512)
#define ACT_GAIN 1.41421356237f  // sqrt(2)
#define CLAMP_V 256.0f

typedef __attribute__((ext_vector_type(8))) short bf16x8;
typedef __attribute__((ext_vector_type(4))) float f32x4;

// Parity tap matrices: G[p][i][a] = u[a-1+2i-p], u = {1,3,3,1}/4 (0 if OOR)
__device__ __constant__ float c_G[2][3][3] = {
    {{0.00f, 0.25f, 0.75f}, {0.75f, 0.75f, 0.25f}, {0.25f, 0.00f, 0.00f}},
    {{0.00f, 0.00f, 0.25f}, {0.25f, 0.75f, 0.75f}, {0.75f, 0.25f, 0.00f}}
};

#define XBF_BYTES ((size_t)NIMG * HP * HP * IN_CH * 2)     // 71,368,704
#define EBF_BYTES ((size_t)9 * 1024 * IN_CH * 2)           //  9,437,184
#define WS_NEED (XBF_BYTES + EBF_BYTES)

// ---------------- x -> padded NHWC bf16 [16][66][66][512] ----------------
__global__ __launch_bounds__(256) void xpose_kernel(const float* __restrict__ x,
                                                    __hip_bfloat16* __restrict__ xbf) {
    const int n = blockIdx.z;
    const int hp = blockIdx.y;        // 0..65
    const int c0 = blockIdx.x << 6;   // 8 chunks of 64 channels
    const int tid = threadIdx.x;
    const size_t obase = ((size_t)n * HP + hp) * HP;  // pixel-row base

    if (hp == 0 || hp == HP - 1) {
        for (int idx = tid; idx < HP * 64; idx += 256) {
            int wp = idx >> 6, c = idx & 63;
            xbf[(obase + wp) * IN_CH + c0 + c] = __float2bfloat16(0.f);
        }
        return;
    }
    __shared__ float tile[64][65];
    {
        int cc = tid >> 6, w = tid & 63;
        for (int cb = 0; cb < 64; cb += 4)
            tile[cb + cc][w] =
                x[(((size_t)n * IN_CH + c0 + cb + cc) * HIN + (hp - 1)) * HIN + w];
    }
    __syncthreads();
    {
        int c = tid & 63, wg = tid >> 6;
        for (int wb = 0; wb < 64; wb += 4) {
            int w2 = wb + wg;
            xbf[(obase + (w2 + 1)) * IN_CH + c0 + c] = __float2bfloat16(tile[c][w2]);
        }
        if (tid < 128) {
            int which = tid >> 6, c2 = tid & 63;
            xbf[(obase + (which ? (HP - 1) : 0)) * IN_CH + c0 + c2] = __float2bfloat16(0.f);
        }
    }
}

// ---------------- w -> E bf16 [9(tap)][1024(oc*4+par)][512(c)] ----------------
__global__ __launch_bounds__(256) void build_ebf_kernel(const float* __restrict__ w,
                                                        __hip_bfloat16* __restrict__ ebf) {
    int gid = blockIdx.x * 256 + threadIdx.x;  // oc*512 + c
    if (gid >= OUT_CH * IN_CH) return;
    int oc = gid >> 9, c = gid & 511;
    float wm[3][3];
    const float* wp = w + (size_t)gid * 9;
#pragma unroll
    for (int a = 0; a < 3; ++a)
#pragma unroll
        for (int b = 0; b < 3; ++b) wm[a][b] = wp[a * 3 + b] * WSCALE;
#pragma unroll
    for (int i = 0; i < 3; ++i)
#pragma unroll
        for (int j = 0; j < 3; ++j)
#pragma unroll
            for (int pu = 0; pu < 2; ++pu)
#pragma unroll
                for (int pv = 0; pv < 2; ++pv) {
                    float s = 0.f;
#pragma unroll
                    for (int a = 0; a < 3; ++a)
#pragma unroll
                        for (int b = 0; b < 3; ++b)
                            s += wm[a][b] * c_G[pu][i][a] * c_G[pv][j][b];
                    ebf[((size_t)(i * 3 + j) * 1024 + oc * 4 + pu * 2 + pv) * IN_CH + c] =
                        __float2bfloat16(s);
                }
}

// ---------------- 256x256 8-phase MFMA implicit-GEMM conv ----------------
// M = 65536 quads (256 tiles of 16x16 quads), N = 1024 (4 tiles), K = 9*512 (72 BK=64 tiles)
// LDS: 8 half-slots of 16 KiB: slot = (tile&1)*4 + mat*2 + khalf, layout [256 rows][32 ch],
// 64B rows with 16B-slot XOR swizzle (slot ^ (row&3)) applied via pre-swizzled global src.
__global__ __launch_bounds__(512, 2) void mfma_conv8_kernel(
    const __hip_bfloat16* __restrict__ xbf, const __hip_bfloat16* __restrict__ ebf,
    const float* __restrict__ bias, float* __restrict__ out) {
    __shared__ __align__(16) char lds[131072];

    const int tid = threadIdx.x;
    const int lane = tid & 63;
    const int wid = tid >> 6;      // 0..7
    const int wy = wid >> 2;       // 0..1 : M half (128 rows)
    const int wx = wid & 3;        // 0..3 : N quarter (64 cols)
    const int lm = lane & 15, lk = lane >> 4;

    // XCD-chunked swizzle: XCD k gets contiguous work ids [k*128, k*128+128)
    const int bid = blockIdx.x;
    const int wkid = ((bid & 7) << 7) + (bid >> 3);
    const int mtile = wkid >> 2;
    const int ntile = wkid & 3;
    const int n = mtile >> 4;
    const int sub = mtile & 15;
    const int qh0 = (sub >> 2) << 4;
    const int qw0 = (sub & 3) << 4;
    const int n0 = ntile << 8;

    // staging per-thread constants
    const int qc_s = lane >> 2;                                // row-within-16 / quad col
    const int src_slot = (((lane & 3) ^ (qc_s & 3)) << 3);     // swizzled channel sub-offset

    f32x4 acc[8][4];
#pragma unroll
    for (int mi = 0; mi < 8; ++mi)
#pragma unroll
        for (int ni = 0; ni < 4; ++ni) acc[mi][ni] = (f32x4)(0.f);

    // stage one 16 KiB half-slot: item s = tile*4 + part, part: 0=AK0 1=BK0 2=AK1 3=BK1
    auto stage = [&](int s) {
        const int tt2 = s >> 2;
        const int part = s & 3;
        const int mat = part & 1;
        const int kh = part >> 1;
        const int tap = tt2 >> 3;
        const int chan = ((tt2 & 7) << 6) + (kh << 5) + src_slot;
        char* dst = lds + ((((tt2 & 1) << 2) | (mat << 1) | kh) << 14) + (wid << 10);
        if (mat == 0) {
            const int fi = (tap * 171) >> 9;
            const int fj = tap - fi * 3;
            const int wp = qw0 + fj + qc_s;
#pragma unroll
            for (int c = 0; c < 2; ++c) {
                const int hp = qh0 + fi + (c << 3) + wid;
                const __hip_bfloat16* src =
                    xbf + (((size_t)n * HP + hp) * HP + wp) * IN_CH + chan;
                __builtin_amdgcn_global_load_lds(
                    (const __attribute__((address_space(1))) unsigned int*)src,
                    (__attribute__((address_space(3))) unsigned int*)(dst + (c << 13)),
                    16, 0, 0);
            }
        } else {
#pragma unroll
            for (int c = 0; c < 2; ++c) {
                const int r = (c << 7) + (wid << 4) + qc_s;
                const __hip_bfloat16* src =
                    ebf + ((size_t)tap * 1024 + n0 + r) * IN_CH + chan;
                __builtin_amdgcn_global_load_lds(
                    (const __attribute__((address_space(1))) unsigned int*)src,
                    (__attribute__((address_space(3))) unsigned int*)(dst + (c << 13)),
                    16, 0, 0);
            }
        }
    };

    // ---- prologue: items 0..5, then allow newest 2 halves outstanding ----
#pragma unroll
    for (int s = 0; s < 6; ++s) stage(s);
    asm volatile("s_waitcnt vmcnt(4)" ::: "memory");
    __builtin_amdgcn_s_barrier();

    // ---- main loop: 72 K-tiles x 4 phases ----
    const int rsw = (lm & 3);  // read-side swizzle key (= row&3 for all frag rows)
#pragma unroll 1
    for (int tt = 0; tt < 72; ++tt) {
        const int par = (tt & 1) << 2;
        bf16x8 bfr[4];
#pragma unroll
        for (int p = 0; p < 4; ++p) {
            const int kh = p >> 1, mh = p & 1;
            const char* aslot = lds + ((par | kh) << 14);
            const char* bslot = lds + ((par | 2 | kh) << 14);
            bf16x8 af[4];
#pragma unroll
            for (int mi = 0; mi < 4; ++mi) {
                const int r = (wy << 7) + (mh << 6) + (mi << 4) + lm;
                af[mi] = *(const bf16x8*)(aslot + r * 64 + ((lk ^ rsw) << 4));
            }
            if (mh == 0) {
#pragma unroll
                for (int ni = 0; ni < 4; ++ni) {
                    const int r = (wx << 6) + (ni << 4) + lm;
                    bfr[ni] = *(const bf16x8*)(bslot + r * 64 + ((lk ^ rsw) << 4));
                }
            }
            const int s = tt * 4 + p + 6;
            if (s < 288) stage(s);
            __builtin_amdgcn_s_barrier();
            asm volatile("s_waitcnt lgkmcnt(0)" ::: "memory");
            __builtin_amdgcn_s_setprio(1);
#pragma unroll
            for (int mi = 0; mi < 4; ++mi)
#pragma unroll
                for (int ni = 0; ni < 4; ++ni)
                    acc[mh * 4 + mi][ni] = __builtin_amdgcn_mfma_f32_16x16x32_bf16(
                        af[mi], bfr[ni], acc[mh * 4 + mi][ni], 0, 0, 0);
            __builtin_amdgcn_s_setprio(0);
            if (p == 3) {
                if (tt < 70)
                    asm volatile("s_waitcnt vmcnt(4)" ::: "memory");
                else
                    asm volatile("s_waitcnt vmcnt(0)" ::: "memory");
            }
            __builtin_amdgcn_s_barrier();
        }
    }

    // ---- epilogue: bias + leaky-relu*sqrt2 + clamp, scatter to NCHW ----
    float bv[4];
#pragma unroll
    for (int ni = 0; ni < 4; ++ni)
        bv[ni] = bias[(n0 + (wx << 6) + (ni << 4) + lm) >> 2];
#pragma unroll
    for (int mi8 = 0; mi8 < 8; ++mi8) {
#pragma unroll
        for (int v = 0; v < 4; ++v) {
            const int row = (wy << 7) + (mi8 << 4) + (lk << 2) + v;
            const int qr = row >> 4, qc = row & 15;
            const int hb = 2 * (qh0 + qr), wb = 2 * (qw0 + qc);
#pragma unroll
            for (int ni = 0; ni < 4; ++ni) {
                const int nn = n0 + (wx << 6) + (ni << 4) + lm;
                const int oc = nn >> 2, pu = (nn >> 1) & 1, pv = nn & 1;
                float val = acc[mi8][ni][v] + bv[ni];
                val = (val >= 0.f ? val : 0.2f * val) * ACT_GAIN;
                val = fminf(fmaxf(val, -CLAMP_V), CLAMP_V);
                out[(((size_t)n * OUT_CH + oc) * HOUT + (hb + pu)) * HOUT + (wb + pv)] = val;
            }
        }
    }
}

// ---------------- fallback (R1 proven path) if workspace too small ----------------
__global__ void build_e_kernel(const float* __restrict__ w, float* __restrict__ e_ws) {
    int gid = blockIdx.x * blockDim.x + threadIdx.x;
    if (gid >= OUT_CH * IN_CH) return;
    float wm[3][3];
    const float* wp = w + (size_t)gid * 9;
#pragma unroll
    for (int a = 0; a < 3; ++a)
#pragma unroll
        for (int b = 0; b < 3; ++b) wm[a][b] = wp[a * 3 + b] * WSCALE;
    float* op = e_ws + (size_t)gid * 36;
#pragma unroll
    for (int i = 0; i < 3; ++i)
#pragma unroll
        for (int j = 0; j < 3; ++j)
#pragma unroll
            for (int pu = 0; pu < 2; ++pu)
#pragma unroll
                for (int pv = 0; pv < 2; ++pv) {
                    float s = 0.f;
#pragma unroll
                    for (int a = 0; a < 3; ++a)
#pragma unroll
                        for (int b = 0; b < 3; ++b)
                            s += wm[a][b] * c_G[pu][i][a] * c_G[pv][j][b];
                    op[(i * 3 + j) * 4 + pu * 2 + pv] = s;
                }
}

#define OGB 8
#define CB 8
#define QT 16
__global__ __launch_bounds__(256) void fused_conv_kernel(
    const float* __restrict__ x, const float* __restrict__ e_ws,
    const float* __restrict__ bias, float* __restrict__ out) {
    __shared__ float sX[CB][18][19];
    __shared__ float4 sE[OGB * CB * 9];
    const int tid = threadIdx.x;
    const int o2 = tid >> 7;
    const int qy = (tid >> 3) & 15;
    const int qxp = tid & 7;
    const int tileIdx = blockIdx.x;
    const int hq0 = (tileIdx >> 2) * QT;
    const int wq0 = (tileIdx & 3) * QT;
    const int o0 = blockIdx.y * OGB;
    const int n = blockIdx.z;
    float4 acc[2][4];
#pragma unroll
    for (int q = 0; q < 2; ++q)
#pragma unroll
        for (int oo = 0; oo < 4; ++oo) acc[q][oo] = make_float4(0.f, 0.f, 0.f, 0.f);
    for (int c0 = 0; c0 < IN_CH; c0 += CB) {
        for (int idx = tid; idx < CB * 18 * 18; idx += 256) {
            int cc = idx / 324;
            int rem = idx - cc * 324;
            int r = rem / 18;
            int col = rem - r * 18;
            int h = hq0 - 1 + r;
            int ww = wq0 - 1 + col;
            float v = 0.f;
            if (h >= 0 && h < HIN && ww >= 0 && ww < HIN)
                v = x[(((size_t)n * IN_CH + (c0 + cc)) * HIN + h) * HIN + ww];
            sX[cc][r][col] = v;
        }
        {
            float* sEf = (float*)sE;
            for (int idx = tid; idx < OGB * CB * 36; idx += 256) {
                int ol = idx / (CB * 36);
                int rem = idx - ol * (CB * 36);
                sEf[ol * (CB * 36) + rem] =
                    e_ws[((size_t)(o0 + ol) * IN_CH + c0) * 36 + rem];
            }
        }
        __syncthreads();
#pragma unroll 1
        for (int cc = 0; cc < CB; ++cc) {
#pragma unroll
            for (int i = 0; i < 3; ++i) {
#pragma unroll
                for (int j = 0; j < 3; ++j) {
                    float xv0 = sX[cc][qy + i][2 * qxp + j];
                    float xv1 = sX[cc][qy + i][2 * qxp + 1 + j];
#pragma unroll
                    for (int oo = 0; oo < 4; ++oo) {
                        float4 e = sE[((o2 * 4 + oo) * CB + cc) * 9 + i * 3 + j];
                        acc[0][oo].x += xv0 * e.x; acc[0][oo].y += xv0 * e.y;
                        acc[0][oo].z += xv0 * e.z; acc[0][oo].w += xv0 * e.w;
                        acc[1][oo].x += xv1 * e.x; acc[1][oo].y += xv1 * e.y;
                        acc[1][oo].z += xv1 * e.z; acc[1][oo].w += xv1 * e.w;
                    }
                }
            }
        }
        __syncthreads();
    }
#pragma unroll
    for (int q = 0; q < 2; ++q) {
        int qx = 2 * qxp + q;
        int u0 = 2 * (hq0 + qy);
        int v0 = 2 * (wq0 + qx);
#pragma unroll
        for (int oo = 0; oo < 4; ++oo) {
            int o = o0 + o2 * 4 + oo;
            float b = bias[o];
            float vals[4] = {acc[q][oo].x, acc[q][oo].y, acc[q][oo].z, acc[q][oo].w};
#pragma unroll
            for (int p = 0; p < 4; ++p) {
                int pu = p >> 1, pv = p & 1;
                float v = vals[p] + b;
                v = (v >= 0.f ? v : 0.2f * v) * ACT_GAIN;
                v = fminf(fmaxf(v, -CLAMP_V), CLAMP_V);
                out[(((size_t)n * OUT_CH + o) * HOUT + (u0 + pu)) * HOUT + (v0 + pv)] = v;
            }
        }
    }
}

extern "C" void kernel_launch(void* const* d_in, const int* in_sizes, int n_in,
                              void* d_out, int out_size, void* d_ws, size_t ws_size,
                              hipStream_t stream) {
    const float* x = (const float*)d_in[0];
    const float* w = (const float*)d_in[1];
    const float* bias = (const float*)d_in[2];
    float* out = (float*)d_out;

    if (ws_size >= WS_NEED) {
        __hip_bfloat16* xbf = (__hip_bfloat16*)d_ws;
        __hip_bfloat16* ebf = (__hip_bfloat16*)((char*)d_ws + XBF_BYTES);
        xpose_kernel<<<dim3(8, HP, NIMG), 256, 0, stream>>>(x, xbf);
        build_ebf_kernel<<<(OUT_CH * IN_CH + 255) / 256, 256, 0, stream>>>(w, ebf);
        mfma_conv8_kernel<<<dim3(1024), 512, 0, stream>>>(xbf, ebf, bias, out);
    } else {
        float* e_ws = (float*)d_ws;
        build_e_kernel<<<(OUT_CH * IN_CH + 255) / 256, 256, 0, stream>>>(w, e_ws);
        dim3 grid(16, OUT_CH / OGB, NIMG);
        fused_conv_kernel<<<grid, 256, 0, stream>>>(x, e_ws, bias, out);
    }
}

// Round 4
// 685.799 us; speedup vs baseline: 11.5683x; 1.0286x over previous
//
#include <hip/hip_runtime.h>
#include <hip/hip_bf16.h>

#define NIMG 16
#define IN_CH 512
#define OUT_CH 256
#define HIN 64
#define HOUT 128
#define HP 66  // padded spatial (1-pixel zero halo)

#define WSCALE 0.014731391f      // 1/sqrt(9*512)
#define ACT_GAIN 1.41421356237f  // sqrt(2)
#define CLAMP_V 256.0f

typedef __attribute__((ext_vector_type(8))) short bf16x8;
typedef __attribute__((ext_vector_type(4))) float f32x4;

// Parity tap matrices: G[p][i][a] = u[a-1+2i-p], u = {1,3,3,1}/4 (0 if OOR)
__device__ __constant__ float c_G[2][3][3] = {
    {{0.00f, 0.25f, 0.75f}, {0.75f, 0.75f, 0.25f}, {0.25f, 0.00f, 0.00f}},
    {{0.00f, 0.00f, 0.25f}, {0.25f, 0.75f, 0.75f}, {0.75f, 0.25f, 0.00f}}
};

#define XBF_BYTES ((size_t)NIMG * HP * HP * IN_CH * 2)     // 71,368,704
#define EBF_BYTES ((size_t)9 * 1024 * IN_CH * 2)           //  9,437,184
#define WS_NEED (XBF_BYTES + EBF_BYTES)

// ---------------- x -> padded NHWC bf16 [16][66][66][512] ----------------
__global__ __launch_bounds__(256) void xpose_kernel(const float* __restrict__ x,
                                                    __hip_bfloat16* __restrict__ xbf) {
    const int n = blockIdx.z;
    const int hp = blockIdx.y;        // 0..65
    const int c0 = blockIdx.x << 6;   // 8 chunks of 64 channels
    const int tid = threadIdx.x;
    const size_t obase = ((size_t)n * HP + hp) * HP;  // pixel-row base

    if (hp == 0 || hp == HP - 1) {
        for (int idx = tid; idx < HP * 64; idx += 256) {
            int wp = idx >> 6, c = idx & 63;
            xbf[(obase + wp) * IN_CH + c0 + c] = __float2bfloat16(0.f);
        }
        return;
    }
    __shared__ float tile[64][65];
    {
        int cc = tid >> 6, w = tid & 63;
        for (int cb = 0; cb < 64; cb += 4)
            tile[cb + cc][w] =
                x[(((size_t)n * IN_CH + c0 + cb + cc) * HIN + (hp - 1)) * HIN + w];
    }
    __syncthreads();
    {
        int c = tid & 63, wg = tid >> 6;
        for (int wb = 0; wb < 64; wb += 4) {
            int w2 = wb + wg;
            xbf[(obase + (w2 + 1)) * IN_CH + c0 + c] = __float2bfloat16(tile[c][w2]);
        }
        if (tid < 128) {
            int which = tid >> 6, c2 = tid & 63;
            xbf[(obase + (which ? (HP - 1) : 0)) * IN_CH + c0 + c2] = __float2bfloat16(0.f);
        }
    }
}

// ---------------- w -> E bf16 [9(tap)][1024(oc*4+par)][512(c)] ----------------
__global__ __launch_bounds__(256) void build_ebf_kernel(const float* __restrict__ w,
                                                        __hip_bfloat16* __restrict__ ebf) {
    int gid = blockIdx.x * 256 + threadIdx.x;  // oc*512 + c
    if (gid >= OUT_CH * IN_CH) return;
    int oc = gid >> 9, c = gid & 511;
    float wm[3][3];
    const float* wp = w + (size_t)gid * 9;
#pragma unroll
    for (int a = 0; a < 3; ++a)
#pragma unroll
        for (int b = 0; b < 3; ++b) wm[a][b] = wp[a * 3 + b] * WSCALE;
#pragma unroll
    for (int i = 0; i < 3; ++i)
#pragma unroll
        for (int j = 0; j < 3; ++j)
#pragma unroll
            for (int pu = 0; pu < 2; ++pu)
#pragma unroll
                for (int pv = 0; pv < 2; ++pv) {
                    float s = 0.f;
#pragma unroll
                    for (int a = 0; a < 3; ++a)
#pragma unroll
                        for (int b = 0; b < 3; ++b)
                            s += wm[a][b] * c_G[pu][i][a] * c_G[pv][j][b];
                    ebf[((size_t)(i * 3 + j) * 1024 + oc * 4 + pu * 2 + pv) * IN_CH + c] =
                        __float2bfloat16(s);
                }
}

// ---------------- 256x256 8-phase MFMA implicit-GEMM conv ----------------
// M = 65536 quads (256 tiles of 16x16 quads), N = 1024 (4 tiles), K = 9*512 (72 BK=64 tiles)
// LDS: 8 half-slots of 16 KiB: slot = (tile&1)*4 + mat*2 + khalf, layout [256 rows][32 ch].
// Rows are 64 B (16 banks), so the 16B-slot bank group is (4*row + slot) mod 8:
// swizzle key must be (row>>1)&3 (NOT row&3) to spread 16-lane phases over all 8
// groups -> 2 words/bank (free). Applied via pre-swizzled global src (linear LDS dest).
__global__ __launch_bounds__(512, 2) void mfma_conv8_kernel(
    const __hip_bfloat16* __restrict__ xbf, const __hip_bfloat16* __restrict__ ebf,
    const float* __restrict__ bias, float* __restrict__ out) {
    __shared__ __align__(16) char lds[131072];

    const int tid = threadIdx.x;
    const int lane = tid & 63;
    const int wid = tid >> 6;      // 0..7
    const int wy = wid >> 2;       // 0..1 : M half (128 rows)
    const int wx = wid & 3;        // 0..3 : N quarter (64 cols)
    const int lm = lane & 15, lk = lane >> 4;

    // XCD-chunked swizzle: XCD k gets contiguous work ids [k*128, k*128+128)
    const int bid = blockIdx.x;
    const int wkid = ((bid & 7) << 7) + (bid >> 3);
    const int mtile = wkid >> 2;
    const int ntile = wkid & 3;
    const int n = mtile >> 4;
    const int sub = mtile & 15;
    const int qh0 = (sub >> 2) << 4;
    const int qw0 = (sub & 3) << 4;
    const int n0 = ntile << 8;

    // staging per-thread constants; LDS row = (c<<7)+(wid<<4)+(lane>>2), so
    // (row>>1)&3 == (lane>>3)&3 for the swizzle key.
    const int qc_s = lane >> 2;                                   // row-within-16
    const int src_slot = (((lane & 3) ^ ((lane >> 3) & 3)) << 3); // swizzled channel sub-offset

    f32x4 acc[8][4];
#pragma unroll
    for (int mi = 0; mi < 8; ++mi)
#pragma unroll
        for (int ni = 0; ni < 4; ++ni) acc[mi][ni] = (f32x4)(0.f);

    // stage one 16 KiB half-slot: item s = tile*4 + part, part: 0=AK0 1=BK0 2=AK1 3=BK1
    auto stage = [&](int s) {
        const int tt2 = s >> 2;
        const int part = s & 3;
        const int mat = part & 1;
        const int kh = part >> 1;
        const int tap = tt2 >> 3;
        const int chan = ((tt2 & 7) << 6) + (kh << 5) + src_slot;
        char* dst = lds + ((((tt2 & 1) << 2) | (mat << 1) | kh) << 14) + (wid << 10);
        if (mat == 0) {
            const int fi = (tap * 171) >> 9;
            const int fj = tap - fi * 3;
            const int wp = qw0 + fj + qc_s;
#pragma unroll
            for (int c = 0; c < 2; ++c) {
                const int hp = qh0 + fi + (c << 3) + wid;
                const __hip_bfloat16* src =
                    xbf + (((size_t)n * HP + hp) * HP + wp) * IN_CH + chan;
                __builtin_amdgcn_global_load_lds(
                    (const __attribute__((address_space(1))) unsigned int*)src,
                    (__attribute__((address_space(3))) unsigned int*)(dst + (c << 13)),
                    16, 0, 0);
            }
        } else {
#pragma unroll
            for (int c = 0; c < 2; ++c) {
                const int r = (c << 7) + (wid << 4) + qc_s;
                const __hip_bfloat16* src =
                    ebf + ((size_t)tap * 1024 + n0 + r) * IN_CH + chan;
                __builtin_amdgcn_global_load_lds(
                    (const __attribute__((address_space(1))) unsigned int*)src,
                    (__attribute__((address_space(3))) unsigned int*)(dst + (c << 13)),
                    16, 0, 0);
            }
        }
    };

    // ---- prologue: items 0..5, then allow newest 2 halves outstanding ----
#pragma unroll
    for (int s = 0; s < 6; ++s) stage(s);
    asm volatile("s_waitcnt vmcnt(4)" ::: "memory");
    __builtin_amdgcn_s_barrier();

    // ---- main loop: 72 K-tiles x 4 phases ----
    const int rsw = (lm >> 1) & 3;  // read-side swizzle key (= (row>>1)&3 for all frag rows)
#pragma unroll 1
    for (int tt = 0; tt < 72; ++tt) {
        const int par = (tt & 1) << 2;
        bf16x8 bfr[4];
#pragma unroll
        for (int p = 0; p < 4; ++p) {
            const int kh = p >> 1, mh = p & 1;
            const char* aslot = lds + ((par | kh) << 14);
            const char* bslot = lds + ((par | 2 | kh) << 14);
            bf16x8 af[4];
#pragma unroll
            for (int mi = 0; mi < 4; ++mi) {
                const int r = (wy << 7) + (mh << 6) + (mi << 4) + lm;
                af[mi] = *(const bf16x8*)(aslot + r * 64 + ((lk ^ rsw) << 4));
            }
            if (mh == 0) {
#pragma unroll
                for (int ni = 0; ni < 4; ++ni) {
                    const int r = (wx << 6) + (ni << 4) + lm;
                    bfr[ni] = *(const bf16x8*)(bslot + r * 64 + ((lk ^ rsw) << 4));
                }
            }
            const int s = tt * 4 + p + 6;
            if (s < 288) stage(s);
            __builtin_amdgcn_s_barrier();
            asm volatile("s_waitcnt lgkmcnt(0)" ::: "memory");
            __builtin_amdgcn_s_setprio(1);
#pragma unroll
            for (int mi = 0; mi < 4; ++mi)
#pragma unroll
                for (int ni = 0; ni < 4; ++ni)
                    acc[mh * 4 + mi][ni] = __builtin_amdgcn_mfma_f32_16x16x32_bf16(
                        af[mi], bfr[ni], acc[mh * 4 + mi][ni], 0, 0, 0);
            __builtin_amdgcn_s_setprio(0);
            if (p == 3) {
                if (tt < 70)
                    asm volatile("s_waitcnt vmcnt(4)" ::: "memory");
                else
                    asm volatile("s_waitcnt vmcnt(0)" ::: "memory");
            }
            __builtin_amdgcn_s_barrier();
        }
    }

    // ---- epilogue: bias + leaky-relu*sqrt2 + clamp, scatter to NCHW ----
    float bv[4];
#pragma unroll
    for (int ni = 0; ni < 4; ++ni)
        bv[ni] = bias[(n0 + (wx << 6) + (ni << 4) + lm) >> 2];
#pragma unroll
    for (int mi8 = 0; mi8 < 8; ++mi8) {
#pragma unroll
        for (int v = 0; v < 4; ++v) {
            const int row = (wy << 7) + (mi8 << 4) + (lk << 2) + v;
            const int qr = row >> 4, qc = row & 15;
            const int hb = 2 * (qh0 + qr), wb = 2 * (qw0 + qc);
#pragma unroll
            for (int ni = 0; ni < 4; ++ni) {
                const int nn = n0 + (wx << 6) + (ni << 4) + lm;
                const int oc = nn >> 2, pu = (nn >> 1) & 1, pv = nn & 1;
                float val = acc[mi8][ni][v] + bv[ni];
                val = (val >= 0.f ? val : 0.2f * val) * ACT_GAIN;
                val = fminf(fmaxf(val, -CLAMP_V), CLAMP_V);
                out[(((size_t)n * OUT_CH + oc) * HOUT + (hb + pu)) * HOUT + (wb + pv)] = val;
            }
        }
    }
}

// ---------------- fallback (R1 proven path) if workspace too small ----------------
__global__ void build_e_kernel(const float* __restrict__ w, float* __restrict__ e_ws) {
    int gid = blockIdx.x * blockDim.x + threadIdx.x;
    if (gid >= OUT_CH * IN_CH) return;
    float wm[3][3];
    const float* wp = w + (size_t)gid * 9;
#pragma unroll
    for (int a = 0; a < 3; ++a)
#pragma unroll
        for (int b = 0; b < 3; ++b) wm[a][b] = wp[a * 3 + b] * WSCALE;
    float* op = e_ws + (size_t)gid * 36;
#pragma unroll
    for (int i = 0; i < 3; ++i)
#pragma unroll
        for (int j = 0; j < 3; ++j)
#pragma unroll
            for (int pu = 0; pu < 2; ++pu)
#pragma unroll
                for (int pv = 0; pv < 2; ++pv) {
                    float s = 0.f;
#pragma unroll
                    for (int a = 0; a < 3; ++a)
#pragma unroll
                        for (int b = 0; b < 3; ++b)
                            s += wm[a][b] * c_G[pu][i][a] * c_G[pv][j][b];
                    op[(i * 3 + j) * 4 + pu * 2 + pv] = s;
                }
}

#define OGB 8
#define CB 8
#define QT 16
__global__ __launch_bounds__(256) void fused_conv_kernel(
    const float* __restrict__ x, const float* __restrict__ e_ws,
    const float* __restrict__ bias, float* __restrict__ out) {
    __shared__ float sX[CB][18][19];
    __shared__ float4 sE[OGB * CB * 9];
    const int tid = threadIdx.x;
    const int o2 = tid >> 7;
    const int qy = (tid >> 3) & 15;
    const int qxp = tid & 7;
    const int tileIdx = blockIdx.x;
    const int hq0 = (tileIdx >> 2) * QT;
    const int wq0 = (tileIdx & 3) * QT;
    const int o0 = blockIdx.y * OGB;
    const int n = blockIdx.z;
    float4 acc[2][4];
#pragma unroll
    for (int q = 0; q < 2; ++q)
#pragma unroll
        for (int oo = 0; oo < 4; ++oo) acc[q][oo] = make_float4(0.f, 0.f, 0.f, 0.f);
    for (int c0 = 0; c0 < IN_CH; c0 += CB) {
        for (int idx = tid; idx < CB * 18 * 18; idx += 256) {
            int cc = idx / 324;
            int rem = idx - cc * 324;
            int r = rem / 18;
            int col = rem - r * 18;
            int h = hq0 - 1 + r;
            int ww = wq0 - 1 + col;
            float v = 0.f;
            if (h >= 0 && h < HIN && ww >= 0 && ww < HIN)
                v = x[(((size_t)n * IN_CH + (c0 + cc)) * HIN + h) * HIN + ww];
            sX[cc][r][col] = v;
        }
        {
            float* sEf = (float*)sE;
            for (int idx = tid; idx < OGB * CB * 36; idx += 256) {
                int ol = idx / (CB * 36);
                int rem = idx - ol * (CB * 36);
                sEf[ol * (CB * 36) + rem] =
                    e_ws[((size_t)(o0 + ol) * IN_CH + c0) * 36 + rem];
            }
        }
        __syncthreads();
#pragma unroll 1
        for (int cc = 0; cc < CB; ++cc) {
#pragma unroll
            for (int i = 0; i < 3; ++i) {
#pragma unroll
                for (int j = 0; j < 3; ++j) {
                    float xv0 = sX[cc][qy + i][2 * qxp + j];
                    float xv1 = sX[cc][qy + i][2 * qxp + 1 + j];
#pragma unroll
                    for (int oo = 0; oo < 4; ++oo) {
                        float4 e = sE[((o2 * 4 + oo) * CB + cc) * 9 + i * 3 + j];
                        acc[0][oo].x += xv0 * e.x; acc[0][oo].y += xv0 * e.y;
                        acc[0][oo].z += xv0 * e.z; acc[0][oo].w += xv0 * e.w;
                        acc[1][oo].x += xv1 * e.x; acc[1][oo].y += xv1 * e.y;
                        acc[1][oo].z += xv1 * e.z; acc[1][oo].w += xv1 * e.w;
                    }
                }
            }
        }
        __syncthreads();
    }
#pragma unroll
    for (int q = 0; q < 2; ++q) {
        int qx = 2 * qxp + q;
        int u0 = 2 * (hq0 + qy);
        int v0 = 2 * (wq0 + qx);
#pragma unroll
        for (int oo = 0; oo < 4; ++oo) {
            int o = o0 + o2 * 4 + oo;
            float b = bias[o];
            float vals[4] = {acc[q][oo].x, acc[q][oo].y, acc[q][oo].z, acc[q][oo].w};
#pragma unroll
            for (int p = 0; p < 4; ++p) {
                int pu = p >> 1, pv = p & 1;
                float v = vals[p] + b;
                v = (v >= 0.f ? v : 0.2f * v) * ACT_GAIN;
                v = fminf(fmaxf(v, -CLAMP_V), CLAMP_V);
                out[(((size_t)n * OUT_CH + o) * HOUT + (u0 + pu)) * HOUT + (v0 + pv)] = v;
            }
        }
    }
}

extern "C" void kernel_launch(void* const* d_in, const int* in_sizes, int n_in,
                              void* d_out, int out_size, void* d_ws, size_t ws_size,
                              hipStream_t stream) {
    const float* x = (const float*)d_in[0];
    const float* w = (const float*)d_in[1];
    const float* bias = (const float*)d_in[2];
    float* out = (float*)d_out;

    if (ws_size >= WS_NEED) {
        __hip_bfloat16* xbf = (__hip_bfloat16*)d_ws;
        __hip_bfloat16* ebf = (__hip_bfloat16*)((char*)d_ws + XBF_BYTES);
        xpose_kernel<<<dim3(8, HP, NIMG), 256, 0, stream>>>(x, xbf);
        build_ebf_kernel<<<(OUT_CH * IN_CH + 255) / 256, 256, 0, stream>>>(w, ebf);
        mfma_conv8_kernel<<<dim3(1024), 512, 0, stream>>>(xbf, ebf, bias, out);
    } else {
        float* e_ws = (float*)d_ws;
        build_e_kernel<<<(OUT_CH * IN_CH + 255) / 256, 256, 0, stream>>>(w, e_ws);
        dim3 grid(16, OUT_CH / OGB, NIMG);
        fused_conv_kernel<<<grid, 256, 0, stream>>>(x, e_ws, bias, out);
    }
}

// Round 5
// 673.186 us; speedup vs baseline: 11.7850x; 1.0187x over previous
//
#include <hip/hip_runtime.h>
#include <hip/hip_bf16.h>

#define NIMG 16
#define IN_CH 512
#define OUT_CH 256
#define HIN 64
#define HOUT 128
#define HP 66  // padded spatial (1-pixel zero halo)

#define WSCALE 0.014731391f      // 1/sqrt(9*512)
#define ACT_GAIN 1.41421356237f  // sqrt(2)
#define CLAMP_V 256.0f

typedef __attribute__((ext_vector_type(8))) short bf16x8;
typedef __attribute__((ext_vector_type(4))) float f32x4;

// Parity tap matrices: G[p][i][a] = u[a-1+2i-p], u = {1,3,3,1}/4 (0 if OOR)
__device__ __constant__ float c_G[2][3][3] = {
    {{0.00f, 0.25f, 0.75f}, {0.75f, 0.75f, 0.25f}, {0.25f, 0.00f, 0.00f}},
    {{0.00f, 0.00f, 0.25f}, {0.25f, 0.75f, 0.75f}, {0.75f, 0.25f, 0.00f}}
};

#define XBF_BYTES ((size_t)NIMG * HP * HP * IN_CH * 2)     // 71,368,704
#define EBF_BYTES ((size_t)9 * 1024 * IN_CH * 2)           //  9,437,184
#define WS_NEED (XBF_BYTES + EBF_BYTES)

// ---------------- x -> padded NHWC bf16 [16][66][66][512] ----------------
__global__ __launch_bounds__(256) void xpose_kernel(const float* __restrict__ x,
                                                    __hip_bfloat16* __restrict__ xbf) {
    const int n = blockIdx.z;
    const int hp = blockIdx.y;        // 0..65
    const int c0 = blockIdx.x << 6;   // 8 chunks of 64 channels
    const int tid = threadIdx.x;
    const size_t obase = ((size_t)n * HP + hp) * HP;  // pixel-row base

    if (hp == 0 || hp == HP - 1) {
        for (int idx = tid; idx < HP * 64; idx += 256) {
            int wp = idx >> 6, c = idx & 63;
            xbf[(obase + wp) * IN_CH + c0 + c] = __float2bfloat16(0.f);
        }
        return;
    }
    __shared__ float tile[64][65];
    {
        int cc = tid >> 6, w = tid & 63;
        for (int cb = 0; cb < 64; cb += 4)
            tile[cb + cc][w] =
                x[(((size_t)n * IN_CH + c0 + cb + cc) * HIN + (hp - 1)) * HIN + w];
    }
    __syncthreads();
    {
        int c = tid & 63, wg = tid >> 6;
        for (int wb = 0; wb < 64; wb += 4) {
            int w2 = wb + wg;
            xbf[(obase + (w2 + 1)) * IN_CH + c0 + c] = __float2bfloat16(tile[c][w2]);
        }
        if (tid < 128) {
            int which = tid >> 6, c2 = tid & 63;
            xbf[(obase + (which ? (HP - 1) : 0)) * IN_CH + c0 + c2] = __float2bfloat16(0.f);
        }
    }
}

// ---------------- w -> E bf16 [9(tap)][1024(oc*4+par)][512(c)] ----------------
__global__ __launch_bounds__(256) void build_ebf_kernel(const float* __restrict__ w,
                                                        __hip_bfloat16* __restrict__ ebf) {
    int gid = blockIdx.x * 256 + threadIdx.x;  // oc*512 + c
    if (gid >= OUT_CH * IN_CH) return;
    int oc = gid >> 9, c = gid & 511;
    float wm[3][3];
    const float* wp = w + (size_t)gid * 9;
#pragma unroll
    for (int a = 0; a < 3; ++a)
#pragma unroll
        for (int b = 0; b < 3; ++b) wm[a][b] = wp[a * 3 + b] * WSCALE;
#pragma unroll
    for (int i = 0; i < 3; ++i)
#pragma unroll
        for (int j = 0; j < 3; ++j)
#pragma unroll
            for (int pu = 0; pu < 2; ++pu)
#pragma unroll
                for (int pv = 0; pv < 2; ++pv) {
                    float s = 0.f;
#pragma unroll
                    for (int a = 0; a < 3; ++a)
#pragma unroll
                        for (int b = 0; b < 3; ++b)
                            s += wm[a][b] * c_G[pu][i][a] * c_G[pv][j][b];
                    ebf[((size_t)(i * 3 + j) * 1024 + oc * 4 + pu * 2 + pv) * IN_CH + c] =
                        __float2bfloat16(s);
                }
}

#define MFMA16(AF, BF, MH)                                                        \
    do {                                                                          \
        _Pragma("unroll") for (int mi = 0; mi < 4; ++mi)                          \
            _Pragma("unroll") for (int ni = 0; ni < 4; ++ni)                      \
                acc[(MH)*4 + mi][ni] = __builtin_amdgcn_mfma_f32_16x16x32_bf16(   \
                    (AF)[mi], (BF)[ni], acc[(MH)*4 + mi][ni], 0, 0, 0);           \
    } while (0)

// ---------------- 256x256 pipelined MFMA implicit-GEMM conv ----------------
// M = 65536 quads (256 tiles of 16x16 quads), N = 1024 (4 tiles), K = 9*512 (72 BK=64 tiles)
// LDS: 8 half-slots of 16 KiB: slot = (tile&1)*4 + mat*2 + khalf, [256 rows][32 ch], 64-B rows,
// 16B-slot XOR swizzle key (row>>1)&3 via pre-swizzled global src (linear LDS dest).
// Fragments for phase p+1 are ds_read-prefetched during phase p; counted lgkmcnt keeps
// them in flight across the phase's MFMA; one barrier per phase; vmcnt(6) at p0/p2
// confirms staged slots >= 1 barrier before their earliest prefetch (ledger-audited).
__global__ __launch_bounds__(512, 2) void mfma_conv8_kernel(
    const __hip_bfloat16* __restrict__ xbf, const __hip_bfloat16* __restrict__ ebf,
    const float* __restrict__ bias, float* __restrict__ out) {
    __shared__ __align__(16) char lds[131072];

    const int tid = threadIdx.x;
    const int lane = tid & 63;
    const int wid = tid >> 6;      // 0..7
    const int wy = wid >> 2;       // 0..1 : M half (128 rows)
    const int wx = wid & 3;        // 0..3 : N quarter (64 cols)
    const int lm = lane & 15, lk = lane >> 4;

    // XCD-chunked swizzle: XCD k gets contiguous work ids [k*128, k*128+128)
    const int bid = blockIdx.x;
    const int wkid = ((bid & 7) << 7) + (bid >> 3);
    const int mtile = wkid >> 2;
    const int ntile = wkid & 3;
    const int n = mtile >> 4;
    const int sub = mtile & 15;
    const int qh0 = (sub >> 2) << 4;
    const int qw0 = (sub & 3) << 4;
    const int n0 = ntile << 8;

    // staging per-thread constants; LDS row = (c<<7)+(wid<<4)+(lane>>2), so
    // (row>>1)&3 == (lane>>3)&3 for the swizzle key.
    const int qc_s = lane >> 2;                                   // row-within-16
    const int src_slot = (((lane & 3) ^ ((lane >> 3) & 3)) << 3); // swizzled channel sub-offset

    f32x4 acc[8][4];
#pragma unroll
    for (int mi = 0; mi < 8; ++mi)
#pragma unroll
        for (int ni = 0; ni < 4; ++ni) acc[mi][ni] = (f32x4)(0.f);

    // stage one 16 KiB half-slot: item s = tile*4 + part, part: 0=AK0 1=BK0 2=AK1 3=BK1
    auto stage = [&](int s) {
        const int tt2 = s >> 2;
        const int part = s & 3;
        const int mat = part & 1;
        const int kh = part >> 1;
        const int tap = tt2 >> 3;
        const int chan = ((tt2 & 7) << 6) + (kh << 5) + src_slot;
        char* dst = lds + ((((tt2 & 1) << 2) | (mat << 1) | kh) << 14) + (wid << 10);
        if (mat == 0) {
            const int fi = (tap * 171) >> 9;
            const int fj = tap - fi * 3;
            const int wp = qw0 + fj + qc_s;
#pragma unroll
            for (int c = 0; c < 2; ++c) {
                const int hp = qh0 + fi + (c << 3) + wid;
                const __hip_bfloat16* src =
                    xbf + (((size_t)n * HP + hp) * HP + wp) * IN_CH + chan;
                __builtin_amdgcn_global_load_lds(
                    (const __attribute__((address_space(1))) unsigned int*)src,
                    (__attribute__((address_space(3))) unsigned int*)(dst + (c << 13)),
                    16, 0, 0);
            }
        } else {
#pragma unroll
            for (int c = 0; c < 2; ++c) {
                const int r = (c << 7) + (wid << 4) + qc_s;
                const __hip_bfloat16* src =
                    ebf + ((size_t)tap * 1024 + n0 + r) * IN_CH + chan;
                __builtin_amdgcn_global_load_lds(
                    (const __attribute__((address_space(1))) unsigned int*)src,
                    (__attribute__((address_space(3))) unsigned int*)(dst + (c << 13)),
                    16, 0, 0);
            }
        }
    };

    const int rsw = (lm >> 1) & 3;  // read-side swizzle key (= (row>>1)&3 for all frag rows)

    // fragment prefetch helpers (compiler-visible ds_read_b128s)
    auto pfA = [&](bf16x8* dst, int par_, int kh, int mh) {
        const char* aslot = lds + (((par_ << 2) | kh) << 14);
        const int rb = (wy << 7) + (mh << 6) + lm;
#pragma unroll
        for (int mi = 0; mi < 4; ++mi)
            dst[mi] = *(const bf16x8*)(aslot + (rb + (mi << 4)) * 64 + ((lk ^ rsw) << 4));
    };
    auto pfB = [&](bf16x8* dst, int par_, int kh) {
        const char* bslot = lds + (((par_ << 2) | 2 | kh) << 14);
        const int rb = (wx << 6) + lm;
#pragma unroll
        for (int ni = 0; ni < 4; ++ni)
            dst[ni] = *(const bf16x8*)(bslot + (rb + (ni << 4)) * 64 + ((lk ^ rsw) << 4));
    };

    // ---- prologue: items 0..5; confirm items 0,1; prefetch phase-0 frags ----
#pragma unroll
    for (int s = 0; s < 6; ++s) stage(s);
    asm volatile("s_waitcnt vmcnt(8)" ::: "memory");
    __builtin_amdgcn_s_barrier();
    __builtin_amdgcn_sched_barrier(0);

    bf16x8 afE[4], afO[4], b0[4], b1[4];
    pfA(afE, 0, 0, 0);
    pfB(b0, 0, 0);

    // ---- main loop: 72 K-tiles x 4 phases, frags prefetched 1 phase ahead ----
#pragma unroll 1
    for (int tt = 0; tt < 72; ++tt) {
        const int par = tt & 1, npar = par ^ 1;
        // ---- p0: compute (kh0, mh0) with afE,b0; prefetch afO(kh0,mh1) ----
        pfA(afO, par, 0, 1);
        if (tt <= 70) stage(4 * tt + 6);
        asm volatile("s_waitcnt lgkmcnt(4)" ::: "memory");
        __builtin_amdgcn_sched_barrier(0);
        __builtin_amdgcn_s_setprio(1);
        MFMA16(afE, b0, 0);
        __builtin_amdgcn_s_setprio(0);
        if (tt < 69)
            asm volatile("s_waitcnt vmcnt(6)" ::: "memory");
        else
            asm volatile("s_waitcnt vmcnt(0)" ::: "memory");
        __builtin_amdgcn_s_barrier();
        __builtin_amdgcn_sched_barrier(0);

        // ---- p1: compute (kh0, mh1) with afO,b0; prefetch afE(kh1,mh0)+b1(kh1) ----
        pfA(afE, par, 1, 0);
        pfB(b1, par, 1);
        if (tt <= 70) stage(4 * tt + 7);
        asm volatile("s_waitcnt lgkmcnt(8)" ::: "memory");
        __builtin_amdgcn_sched_barrier(0);
        __builtin_amdgcn_s_setprio(1);
        MFMA16(afO, b0, 1);
        __builtin_amdgcn_s_setprio(0);
        __builtin_amdgcn_s_barrier();
        __builtin_amdgcn_sched_barrier(0);

        // ---- p2: compute (kh1, mh0) with afE,b1; prefetch afO(kh1,mh1) ----
        pfA(afO, par, 1, 1);
        if (tt <= 69) stage(4 * tt + 8);
        asm volatile("s_waitcnt lgkmcnt(4)" ::: "memory");
        __builtin_amdgcn_sched_barrier(0);
        __builtin_amdgcn_s_setprio(1);
        MFMA16(afE, b1, 0);
        __builtin_amdgcn_s_setprio(0);
        if (tt < 69)
            asm volatile("s_waitcnt vmcnt(6)" ::: "memory");
        else
            asm volatile("s_waitcnt vmcnt(0)" ::: "memory");
        __builtin_amdgcn_s_barrier();
        __builtin_amdgcn_sched_barrier(0);

        // ---- p3: compute (kh1, mh1) with afO,b1; prefetch next tile's afE,b0 ----
        if (tt < 71) {
            pfA(afE, npar, 0, 0);
            pfB(b0, npar, 0);
        }
        if (tt <= 69) stage(4 * tt + 9);
        if (tt < 71)
            asm volatile("s_waitcnt lgkmcnt(8)" ::: "memory");
        else
            asm volatile("s_waitcnt lgkmcnt(0)" ::: "memory");
        __builtin_amdgcn_sched_barrier(0);
        __builtin_amdgcn_s_setprio(1);
        MFMA16(afO, b1, 1);
        __builtin_amdgcn_s_setprio(0);
        __builtin_amdgcn_s_barrier();
        __builtin_amdgcn_sched_barrier(0);
    }

    // ---- epilogue: bias + leaky-relu*sqrt2 + clamp, scatter to NCHW ----
    float bv[4];
#pragma unroll
    for (int ni = 0; ni < 4; ++ni)
        bv[ni] = bias[(n0 + (wx << 6) + (ni << 4) + lm) >> 2];
#pragma unroll
    for (int mi8 = 0; mi8 < 8; ++mi8) {
#pragma unroll
        for (int v = 0; v < 4; ++v) {
            const int row = (wy << 7) + (mi8 << 4) + (lk << 2) + v;
            const int qr = row >> 4, qc = row & 15;
            const int hb = 2 * (qh0 + qr), wb = 2 * (qw0 + qc);
#pragma unroll
            for (int ni = 0; ni < 4; ++ni) {
                const int nn = n0 + (wx << 6) + (ni << 4) + lm;
                const int oc = nn >> 2, pu = (nn >> 1) & 1, pv = nn & 1;
                float val = acc[mi8][ni][v] + bv[ni];
                val = (val >= 0.f ? val : 0.2f * val) * ACT_GAIN;
                val = fminf(fmaxf(val, -CLAMP_V), CLAMP_V);
                out[(((size_t)n * OUT_CH + oc) * HOUT + (hb + pu)) * HOUT + (wb + pv)] = val;
            }
        }
    }
}

// ---------------- fallback (R1 proven path) if workspace too small ----------------
__global__ void build_e_kernel(const float* __restrict__ w, float* __restrict__ e_ws) {
    int gid = blockIdx.x * blockDim.x + threadIdx.x;
    if (gid >= OUT_CH * IN_CH) return;
    float wm[3][3];
    const float* wp = w + (size_t)gid * 9;
#pragma unroll
    for (int a = 0; a < 3; ++a)
#pragma unroll
        for (int b = 0; b < 3; ++b) wm[a][b] = wp[a * 3 + b] * WSCALE;
    float* op = e_ws + (size_t)gid * 36;
#pragma unroll
    for (int i = 0; i < 3; ++i)
#pragma unroll
        for (int j = 0; j < 3; ++j)
#pragma unroll
            for (int pu = 0; pu < 2; ++pu)
#pragma unroll
                for (int pv = 0; pv < 2; ++pv) {
                    float s = 0.f;
#pragma unroll
                    for (int a = 0; a < 3; ++a)
#pragma unroll
                        for (int b = 0; b < 3; ++b)
                            s += wm[a][b] * c_G[pu][i][a] * c_G[pv][j][b];
                    op[(i * 3 + j) * 4 + pu * 2 + pv] = s;
                }
}

#define OGB 8
#define CB 8
#define QT 16
__global__ __launch_bounds__(256) void fused_conv_kernel(
    const float* __restrict__ x, const float* __restrict__ e_ws,
    const float* __restrict__ bias, float* __restrict__ out) {
    __shared__ float sX[CB][18][19];
    __shared__ float4 sE[OGB * CB * 9];
    const int tid = threadIdx.x;
    const int o2 = tid >> 7;
    const int qy = (tid >> 3) & 15;
    const int qxp = tid & 7;
    const int tileIdx = blockIdx.x;
    const int hq0 = (tileIdx >> 2) * QT;
    const int wq0 = (tileIdx & 3) * QT;
    const int o0 = blockIdx.y * OGB;
    const int n = blockIdx.z;
    float4 acc[2][4];
#pragma unroll
    for (int q = 0; q < 2; ++q)
#pragma unroll
        for (int oo = 0; oo < 4; ++oo) acc[q][oo] = make_float4(0.f, 0.f, 0.f, 0.f);
    for (int c0 = 0; c0 < IN_CH; c0 += CB) {
        for (int idx = tid; idx < CB * 18 * 18; idx += 256) {
            int cc = idx / 324;
            int rem = idx - cc * 324;
            int r = rem / 18;
            int col = rem - r * 18;
            int h = hq0 - 1 + r;
            int ww = wq0 - 1 + col;
            float v = 0.f;
            if (h >= 0 && h < HIN && ww >= 0 && ww < HIN)
                v = x[(((size_t)n * IN_CH + (c0 + cc)) * HIN + h) * HIN + ww];
            sX[cc][r][col] = v;
        }
        {
            float* sEf = (float*)sE;
            for (int idx = tid; idx < OGB * CB * 36; idx += 256) {
                int ol = idx / (CB * 36);
                int rem = idx - ol * (CB * 36);
                sEf[ol * (CB * 36) + rem] =
                    e_ws[((size_t)(o0 + ol) * IN_CH + c0) * 36 + rem];
            }
        }
        __syncthreads();
#pragma unroll 1
        for (int cc = 0; cc < CB; ++cc) {
#pragma unroll
            for (int i = 0; i < 3; ++i) {
#pragma unroll
                for (int j = 0; j < 3; ++j) {
                    float xv0 = sX[cc][qy + i][2 * qxp + j];
                    float xv1 = sX[cc][qy + i][2 * qxp + 1 + j];
#pragma unroll
                    for (int oo = 0; oo < 4; ++oo) {
                        float4 e = sE[((o2 * 4 + oo) * CB + cc) * 9 + i * 3 + j];
                        acc[0][oo].x += xv0 * e.x; acc[0][oo].y += xv0 * e.y;
                        acc[0][oo].z += xv0 * e.z; acc[0][oo].w += xv0 * e.w;
                        acc[1][oo].x += xv1 * e.x; acc[1][oo].y += xv1 * e.y;
                        acc[1][oo].z += xv1 * e.z; acc[1][oo].w += xv1 * e.w;
                    }
                }
            }
        }
        __syncthreads();
    }
#pragma unroll
    for (int q = 0; q < 2; ++q) {
        int qx = 2 * qxp + q;
        int u0 = 2 * (hq0 + qy);
        int v0 = 2 * (wq0 + qx);
#pragma unroll
        for (int oo = 0; oo < 4; ++oo) {
            int o = o0 + o2 * 4 + oo;
            float b = bias[o];
            float vals[4] = {acc[q][oo].x, acc[q][oo].y, acc[q][oo].z, acc[q][oo].w};
#pragma unroll
            for (int p = 0; p < 4; ++p) {
                int pu = p >> 1, pv = p & 1;
                float v = vals[p] + b;
                v = (v >= 0.f ? v : 0.2f * v) * ACT_GAIN;
                v = fminf(fmaxf(v, -CLAMP_V), CLAMP_V);
                out[(((size_t)n * OUT_CH + o) * HOUT + (u0 + pu)) * HOUT + (v0 + pv)] = v;
            }
        }
    }
}

extern "C" void kernel_launch(void* const* d_in, const int* in_sizes, int n_in,
                              void* d_out, int out_size, void* d_ws, size_t ws_size,
                              hipStream_t stream) {
    const float* x = (const float*)d_in[0];
    const float* w = (const float*)d_in[1];
    const float* bias = (const float*)d_in[2];
    float* out = (float*)d_out;

    if (ws_size >= WS_NEED) {
        __hip_bfloat16* xbf = (__hip_bfloat16*)d_ws;
        __hip_bfloat16* ebf = (__hip_bfloat16*)((char*)d_ws + XBF_BYTES);
        xpose_kernel<<<dim3(8, HP, NIMG), 256, 0, stream>>>(x, xbf);
        build_ebf_kernel<<<(OUT_CH * IN_CH + 255) / 256, 256, 0, stream>>>(w, ebf);
        mfma_conv8_kernel<<<dim3(1024), 512, 0, stream>>>(xbf, ebf, bias, out);
    } else {
        float* e_ws = (float*)d_ws;
        build_e_kernel<<<(OUT_CH * IN_CH + 255) / 256, 256, 0, stream>>>(w, e_ws);
        dim3 grid(16, OUT_CH / OGB, NIMG);
        fused_conv_kernel<<<grid, 256, 0, stream>>>(x, e_ws, bias, out);
    }
}

// Round 6
// 619.313 us; speedup vs baseline: 12.8102x; 1.0870x over previous
//
#include <hip/hip_runtime.h>
#include <hip/hip_bf16.h>

#define NIMG 16
#define IN_CH 512
#define OUT_CH 256
#define HIN 64
#define HOUT 128
#define HP 66  // padded spatial (1-pixel zero halo)

#define WSCALE 0.014731391f      // 1/sqrt(9*512)
#define ACT_GAIN 1.41421356237f  // sqrt(2)
#define CLAMP_V 256.0f

typedef __attribute__((ext_vector_type(8))) short bf16x8;
typedef __attribute__((ext_vector_type(4))) float f32x4;

// Parity tap matrices: G[p][i][a] = u[a-1+2i-p], u = {1,3,3,1}/4 (0 if OOR)
__device__ __constant__ float c_G[2][3][3] = {
    {{0.00f, 0.25f, 0.75f}, {0.75f, 0.75f, 0.25f}, {0.25f, 0.00f, 0.00f}},
    {{0.00f, 0.00f, 0.25f}, {0.25f, 0.75f, 0.75f}, {0.75f, 0.25f, 0.00f}}
};

#define XBF_BYTES ((size_t)NIMG * HP * HP * IN_CH * 2)     // 71,368,704
#define EBF_BYTES ((size_t)9 * 1024 * IN_CH * 2)           //  9,437,184
#define WS_NEED (XBF_BYTES + EBF_BYTES)

// ---------------- x -> padded NHWC bf16 [16][66][66][512] ----------------
__global__ __launch_bounds__(256) void xpose_kernel(const float* __restrict__ x,
                                                    __hip_bfloat16* __restrict__ xbf) {
    const int n = blockIdx.z;
    const int hp = blockIdx.y;        // 0..65
    const int c0 = blockIdx.x << 6;   // 8 chunks of 64 channels
    const int tid = threadIdx.x;
    const size_t obase = ((size_t)n * HP + hp) * HP;  // pixel-row base

    if (hp == 0 || hp == HP - 1) {
        for (int idx = tid; idx < HP * 64; idx += 256) {
            int wp = idx >> 6, c = idx & 63;
            xbf[(obase + wp) * IN_CH + c0 + c] = __float2bfloat16(0.f);
        }
        return;
    }
    __shared__ float tile[64][65];
    {
        int cc = tid >> 6, w = tid & 63;
        for (int cb = 0; cb < 64; cb += 4)
            tile[cb + cc][w] =
                x[(((size_t)n * IN_CH + c0 + cb + cc) * HIN + (hp - 1)) * HIN + w];
    }
    __syncthreads();
    {
        int c = tid & 63, wg = tid >> 6;
        for (int wb = 0; wb < 64; wb += 4) {
            int w2 = wb + wg;
            xbf[(obase + (w2 + 1)) * IN_CH + c0 + c] = __float2bfloat16(tile[c][w2]);
        }
        if (tid < 128) {
            int which = tid >> 6, c2 = tid & 63;
            xbf[(obase + (which ? (HP - 1) : 0)) * IN_CH + c0 + c2] = __float2bfloat16(0.f);
        }
    }
}

// ---------------- w -> E bf16 [9(tap)][1024(oc*4+par)][512(c)] ----------------
__global__ __launch_bounds__(256) void build_ebf_kernel(const float* __restrict__ w,
                                                        __hip_bfloat16* __restrict__ ebf) {
    int gid = blockIdx.x * 256 + threadIdx.x;  // oc*512 + c
    if (gid >= OUT_CH * IN_CH) return;
    int oc = gid >> 9, c = gid & 511;
    float wm[3][3];
    const float* wp = w + (size_t)gid * 9;
#pragma unroll
    for (int a = 0; a < 3; ++a)
#pragma unroll
        for (int b = 0; b < 3; ++b) wm[a][b] = wp[a * 3 + b] * WSCALE;
#pragma unroll
    for (int i = 0; i < 3; ++i)
#pragma unroll
        for (int j = 0; j < 3; ++j)
#pragma unroll
            for (int pu = 0; pu < 2; ++pu)
#pragma unroll
                for (int pv = 0; pv < 2; ++pv) {
                    float s = 0.f;
#pragma unroll
                    for (int a = 0; a < 3; ++a)
#pragma unroll
                        for (int b = 0; b < 3; ++b)
                            s += wm[a][b] * c_G[pu][i][a] * c_G[pv][j][b];
                    ebf[((size_t)(i * 3 + j) * 1024 + oc * 4 + pu * 2 + pv) * IN_CH + c] =
                        __float2bfloat16(s);
                }
}

#define MFMA16(AF, BF, MH)                                                        \
    do {                                                                          \
        _Pragma("unroll") for (int mi = 0; mi < 4; ++mi)                          \
            _Pragma("unroll") for (int ni = 0; ni < 4; ++ni)                      \
                acc[(MH)*4 + mi][ni] = __builtin_amdgcn_mfma_f32_16x16x32_bf16(   \
                    (AF)[mi], (BF)[ni], acc[(MH)*4 + mi][ni], 0, 0, 0);           \
    } while (0)

// staging constants (elements of bf16)
#define CJA 270336   // +8 rows of padded image: 8*66*512
#define CJB 65536    // +128 rows of E: 128*512
// LDS dst slot constants (bytes), PAR literal
#define DAK1(PAR) (((((PAR) ^ 1) << 2) | 1) << 14)
#define DBK1(PAR) (((((PAR) ^ 1) << 2) | 3) << 14)
#define DAK0(PAR) ((((PAR) << 2) | 0) << 14)
#define DBK0(PAR) ((((PAR) << 2) | 2) << 14)

#define GLL(SRC, DSTOFF)                                                          \
    __builtin_amdgcn_global_load_lds(                                             \
        (const __attribute__((address_space(1))) unsigned int*)(SRC),             \
        (__attribute__((address_space(3))) unsigned int*)(ldsW + (DSTOFF)), 16, 0, 0)

// One K-tile (BK=64), 4 phases, PAR = tile parity as a LITERAL.
// Identical schedule/ledger to R5; all LDS read offsets are compile-time
// immediates off 4 invariant bases; staging via running pointers + SGPR deltas.
#define TILE_ITER(PAR, TT, SP01, SP23, VMS, LGK3, LAST)                           \
    {                                                                             \
        const char* aP = (PAR) ? aBaseO : aBaseE;                                 \
        const char* bP = (PAR) ? bBaseO : bBaseE;                                 \
        /* ---- p0: prefetch afO(kh0,mh1); stage AK1 -> tile TT+1 ---- */         \
        afO[0] = *(const bf16x8*)(aP + 4096);                                     \
        afO[1] = *(const bf16x8*)(aP + 4096 + 1024);                              \
        afO[2] = *(const bf16x8*)(aP + 4096 + 2048);                              \
        afO[3] = *(const bf16x8*)(aP + 4096 + 3072);                              \
        if (SP01) { GLL(pAK1, DAK1(PAR)); GLL(pAK1 + CJA, DAK1(PAR) + 8192); }    \
        pAK1 += ((TT) == 22 || (TT) == 46) ? 32320 : 64;                          \
        asm volatile("s_waitcnt lgkmcnt(4)" ::: "memory");                        \
        __builtin_amdgcn_sched_barrier(0);                                        \
        __builtin_amdgcn_s_setprio(1);                                            \
        MFMA16(afE, b0, 0);                                                       \
        __builtin_amdgcn_s_setprio(0);                                            \
        asm volatile("s_waitcnt " VMS ::: "memory");                              \
        __builtin_amdgcn_s_barrier();                                             \
        __builtin_amdgcn_sched_barrier(0);                                        \
        /* ---- p1: prefetch afE(kh1,mh0)+b1(kh1); stage BK1 -> TT+1 ---- */      \
        afE[0] = *(const bf16x8*)(aP + 16384);                                    \
        afE[1] = *(const bf16x8*)(aP + 16384 + 1024);                             \
        afE[2] = *(const bf16x8*)(aP + 16384 + 2048);                             \
        afE[3] = *(const bf16x8*)(aP + 16384 + 3072);                             \
        b1[0] = *(const bf16x8*)(bP + 16384);                                     \
        b1[1] = *(const bf16x8*)(bP + 16384 + 1024);                              \
        b1[2] = *(const bf16x8*)(bP + 16384 + 2048);                              \
        b1[3] = *(const bf16x8*)(bP + 16384 + 3072);                              \
        if (SP01) { GLL(pBK1, DBK1(PAR)); GLL(pBK1 + CJB, DBK1(PAR) + 8192); }    \
        pBK1 += (((TT) & 7) == 6) ? 523840 : 64;                                  \
        asm volatile("s_waitcnt lgkmcnt(8)" ::: "memory");                        \
        __builtin_amdgcn_sched_barrier(0);                                        \
        __builtin_amdgcn_s_setprio(1);                                            \
        MFMA16(afO, b0, 1);                                                       \
        __builtin_amdgcn_s_setprio(0);                                            \
        __builtin_amdgcn_s_barrier();                                             \
        __builtin_amdgcn_sched_barrier(0);                                        \
        /* ---- p2: prefetch afO(kh1,mh1); stage AK0 -> TT+2 ---- */              \
        afO[0] = *(const bf16x8*)(aP + 20480);                                    \
        afO[1] = *(const bf16x8*)(aP + 20480 + 1024);                             \
        afO[2] = *(const bf16x8*)(aP + 20480 + 2048);                             \
        afO[3] = *(const bf16x8*)(aP + 20480 + 3072);                             \
        if (SP23) { GLL(pAK0, DAK0(PAR)); GLL(pAK0 + CJA, DAK0(PAR) + 8192); }    \
        pAK0 += ((TT) == 21 || (TT) == 45) ? 32320 : 64;                          \
        asm volatile("s_waitcnt lgkmcnt(4)" ::: "memory");                        \
        __builtin_amdgcn_sched_barrier(0);                                        \
        __builtin_amdgcn_s_setprio(1);                                            \
        MFMA16(afE, b1, 0);                                                       \
        __builtin_amdgcn_s_setprio(0);                                            \
        asm volatile("s_waitcnt " VMS ::: "memory");                              \
        __builtin_amdgcn_s_barrier();                                             \
        __builtin_amdgcn_sched_barrier(0);                                        \
        /* ---- p3: prefetch next tile's afE(kh0)+b0(kh0); stage BK0 -> TT+2 */   \
        if (!(LAST)) {                                                            \
            const char* aN = (PAR) ? aBaseE : aBaseO;                             \
            const char* bN = (PAR) ? bBaseE : bBaseO;                             \
            afE[0] = *(const bf16x8*)(aN);                                        \
            afE[1] = *(const bf16x8*)(aN + 1024);                                 \
            afE[2] = *(const bf16x8*)(aN + 2048);                                 \
            afE[3] = *(const bf16x8*)(aN + 3072);                                 \
            b0[0] = *(const bf16x8*)(bN);                                         \
            b0[1] = *(const bf16x8*)(bN + 1024);                                  \
            b0[2] = *(const bf16x8*)(bN + 2048);                                  \
            b0[3] = *(const bf16x8*)(bN + 3072);                                  \
        }                                                                         \
        if (SP23) { GLL(pBK0, DBK0(PAR)); GLL(pBK0 + CJB, DBK0(PAR) + 8192); }    \
        pBK0 += (((TT) & 7) == 5) ? 523840 : 64;                                  \
        asm volatile("s_waitcnt " LGK3 ::: "memory");                             \
        __builtin_amdgcn_sched_barrier(0);                                        \
        __builtin_amdgcn_s_setprio(1);                                            \
        MFMA16(afO, b1, 1);                                                       \
        __builtin_amdgcn_s_setprio(0);                                            \
        __builtin_amdgcn_s_barrier();                                             \
        __builtin_amdgcn_sched_barrier(0);                                        \
    }

// ---------------- 256x256 pipelined MFMA implicit-GEMM conv ----------------
__global__ __launch_bounds__(512, 2) void mfma_conv8_kernel(
    const __hip_bfloat16* __restrict__ xbf, const __hip_bfloat16* __restrict__ ebf,
    const float* __restrict__ bias, float* __restrict__ out) {
    __shared__ __align__(16) char lds[131072];

    const int tid = threadIdx.x;
    const int lane = tid & 63;
    const int wid = tid >> 6;      // 0..7
    const int wy = wid >> 2;       // 0..1 : M half (128 rows)
    const int wx = wid & 3;        // 0..3 : N quarter (64 cols)
    const int lm = lane & 15, lk = lane >> 4;

    const int bid = blockIdx.x;
    const int wkid = ((bid & 7) << 7) + (bid >> 3);
    const int mtile = wkid >> 2;
    const int ntile = wkid & 3;
    const int n = mtile >> 4;
    const int sub = mtile & 15;
    const int qh0 = (sub >> 2) << 4;
    const int qw0 = (sub & 3) << 4;
    const int n0 = ntile << 8;

    const int qc_s = lane >> 2;
    const int src_slot = (((lane & 3) ^ ((lane >> 3) & 3)) << 3);

    f32x4 acc[8][4];
#pragma unroll
    for (int mi = 0; mi < 8; ++mi)
#pragma unroll
        for (int ni = 0; ni < 4; ++ni) acc[mi][ni] = (f32x4)(0.f);

    char* ldsW = lds + (wid << 10);

    // prologue-only generic stage (full address computation; runs 6 times)
    auto stage = [&](int s) {
        const int tt2 = s >> 2;
        const int part = s & 3;
        const int mat = part & 1;
        const int kh = part >> 1;
        const int tap = tt2 >> 3;
        const int chan = ((tt2 & 7) << 6) + (kh << 5) + src_slot;
        char* dst = lds + ((((tt2 & 1) << 2) | (mat << 1) | kh) << 14) + (wid << 10);
        if (mat == 0) {
            const int fi = (tap * 171) >> 9;
            const int fj = tap - fi * 3;
            const int wp = qw0 + fj + qc_s;
#pragma unroll
            for (int c = 0; c < 2; ++c) {
                const int hp = qh0 + fi + (c << 3) + wid;
                const __hip_bfloat16* src =
                    xbf + (((size_t)n * HP + hp) * HP + wp) * IN_CH + chan;
                __builtin_amdgcn_global_load_lds(
                    (const __attribute__((address_space(1))) unsigned int*)src,
                    (__attribute__((address_space(3))) unsigned int*)(dst + (c << 13)),
                    16, 0, 0);
            }
        } else {
#pragma unroll
            for (int c = 0; c < 2; ++c) {
                const int r = (c << 7) + (wid << 4) + qc_s;
                const __hip_bfloat16* src =
                    ebf + ((size_t)tap * 1024 + n0 + r) * IN_CH + chan;
                __builtin_amdgcn_global_load_lds(
                    (const __attribute__((address_space(1))) unsigned int*)src,
                    (__attribute__((address_space(3))) unsigned int*)(dst + (c << 13)),
                    16, 0, 0);
            }
        }
    };

    const int rsw = (lm >> 1) & 3;
    // loop-invariant LDS read bases (byte pointers)
    const char* aBaseE = lds + ((wy << 7) + lm) * 64 + ((lk ^ rsw) << 4);
    const char* aBaseO = aBaseE + 65536;
    const char* bBaseE = lds + 32768 + ((wx << 6) + lm) * 64 + ((lk ^ rsw) << 4);
    const char* bBaseO = bBaseE + 65536;

    // running staging pointers (element arithmetic), init at their first targets
    const __hip_bfloat16* pixA =
        xbf + (((size_t)n * HP + qh0 + wid) * HP + qw0 + qc_s) * IN_CH;
    const __hip_bfloat16* pAK1 = pixA + 96 + src_slot;   // tile 1, kh1
    const __hip_bfloat16* pAK0 = pixA + 128 + src_slot;  // tile 2, kh0
    const __hip_bfloat16* rowB = ebf + ((size_t)n0 + (wid << 4) + qc_s) * IN_CH;
    const __hip_bfloat16* pBK1 = rowB + 96 + src_slot;   // tile 1, kh1
    const __hip_bfloat16* pBK0 = rowB + 128 + src_slot;  // tile 2, kh0

    // ---- prologue: items 0..5; confirm items 0,1; prefetch phase-0 frags ----
#pragma unroll
    for (int s = 0; s < 6; ++s) stage(s);
    asm volatile("s_waitcnt vmcnt(8)" ::: "memory");
    __builtin_amdgcn_s_barrier();
    __builtin_amdgcn_sched_barrier(0);

    bf16x8 afE[4], afO[4], b0[4], b1[4];
    afE[0] = *(const bf16x8*)(aBaseE);
    afE[1] = *(const bf16x8*)(aBaseE + 1024);
    afE[2] = *(const bf16x8*)(aBaseE + 2048);
    afE[3] = *(const bf16x8*)(aBaseE + 3072);
    b0[0] = *(const bf16x8*)(bBaseE);
    b0[1] = *(const bf16x8*)(bBaseE + 1024);
    b0[2] = *(const bf16x8*)(bBaseE + 2048);
    b0[3] = *(const bf16x8*)(bBaseE + 3072);

    // ---- main loop: tiles 0..67 (even count), then peeled tail 68..71 ----
#pragma unroll 1
    for (int tt = 0; tt < 68; tt += 2) {
        TILE_ITER(0, tt, 1, 1, "vmcnt(6)", "lgkmcnt(8)", 0);
        TILE_ITER(1, tt + 1, 1, 1, "vmcnt(6)", "lgkmcnt(8)", 0);
    }
    TILE_ITER(0, 68, 1, 1, "vmcnt(6)", "lgkmcnt(8)", 0);
    TILE_ITER(1, 69, 1, 1, "vmcnt(0)", "lgkmcnt(8)", 0);
    TILE_ITER(0, 70, 1, 0, "vmcnt(0)", "lgkmcnt(8)", 0);
    TILE_ITER(1, 71, 0, 0, "vmcnt(0)", "lgkmcnt(0)", 1);

    // ---- epilogue: bias + leaky-relu*sqrt2 + clamp, scatter to NCHW ----
    float bv[4];
#pragma unroll
    for (int ni = 0; ni < 4; ++ni)
        bv[ni] = bias[(n0 + (wx << 6) + (ni << 4) + lm) >> 2];
#pragma unroll
    for (int mi8 = 0; mi8 < 8; ++mi8) {
#pragma unroll
        for (int v = 0; v < 4; ++v) {
            const int row = (wy << 7) + (mi8 << 4) + (lk << 2) + v;
            const int qr = row >> 4, qc = row & 15;
            const int hb = 2 * (qh0 + qr), wb = 2 * (qw0 + qc);
#pragma unroll
            for (int ni = 0; ni < 4; ++ni) {
                const int nn = n0 + (wx << 6) + (ni << 4) + lm;
                const int oc = nn >> 2, pu = (nn >> 1) & 1, pv = nn & 1;
                float val = acc[mi8][ni][v] + bv[ni];
                val = (val >= 0.f ? val : 0.2f * val) * ACT_GAIN;
                val = fminf(fmaxf(val, -CLAMP_V), CLAMP_V);
                out[(((size_t)n * OUT_CH + oc) * HOUT + (hb + pu)) * HOUT + (wb + pv)] = val;
            }
        }
    }
}

// ---------------- fallback (R1 proven path) if workspace too small ----------------
__global__ void build_e_kernel(const float* __restrict__ w, float* __restrict__ e_ws) {
    int gid = blockIdx.x * blockDim.x + threadIdx.x;
    if (gid >= OUT_CH * IN_CH) return;
    float wm[3][3];
    const float* wp = w + (size_t)gid * 9;
#pragma unroll
    for (int a = 0; a < 3; ++a)
#pragma unroll
        for (int b = 0; b < 3; ++b) wm[a][b] = wp[a * 3 + b] * WSCALE;
    float* op = e_ws + (size_t)gid * 36;
#pragma unroll
    for (int i = 0; i < 3; ++i)
#pragma unroll
        for (int j = 0; j < 3; ++j)
#pragma unroll
            for (int pu = 0; pu < 2; ++pu)
#pragma unroll
                for (int pv = 0; pv < 2; ++pv) {
                    float s = 0.f;
#pragma unroll
                    for (int a = 0; a < 3; ++a)
#pragma unroll
                        for (int b = 0; b < 3; ++b)
                            s += wm[a][b] * c_G[pu][i][a] * c_G[pv][j][b];
                    op[(i * 3 + j) * 4 + pu * 2 + pv] = s;
                }
}

#define OGB 8
#define CB 8
#define QT 16
__global__ __launch_bounds__(256) void fused_conv_kernel(
    const float* __restrict__ x, const float* __restrict__ e_ws,
    const float* __restrict__ bias, float* __restrict__ out) {
    __shared__ float sX[CB][18][19];
    __shared__ float4 sE[OGB * CB * 9];
    const int tid = threadIdx.x;
    const int o2 = tid >> 7;
    const int qy = (tid >> 3) & 15;
    const int qxp = tid & 7;
    const int tileIdx = blockIdx.x;
    const int hq0 = (tileIdx >> 2) * QT;
    const int wq0 = (tileIdx & 3) * QT;
    const int o0 = blockIdx.y * OGB;
    const int n = blockIdx.z;
    float4 acc[2][4];
#pragma unroll
    for (int q = 0; q < 2; ++q)
#pragma unroll
        for (int oo = 0; oo < 4; ++oo) acc[q][oo] = make_float4(0.f, 0.f, 0.f, 0.f);
    for (int c0 = 0; c0 < IN_CH; c0 += CB) {
        for (int idx = tid; idx < CB * 18 * 18; idx += 256) {
            int cc = idx / 324;
            int rem = idx - cc * 324;
            int r = rem / 18;
            int col = rem - r * 18;
            int h = hq0 - 1 + r;
            int ww = wq0 - 1 + col;
            float v = 0.f;
            if (h >= 0 && h < HIN && ww >= 0 && ww < HIN)
                v = x[(((size_t)n * IN_CH + (c0 + cc)) * HIN + h) * HIN + ww];
            sX[cc][r][col] = v;
        }
        {
            float* sEf = (float*)sE;
            for (int idx = tid; idx < OGB * CB * 36; idx += 256) {
                int ol = idx / (CB * 36);
                int rem = idx - ol * (CB * 36);
                sEf[ol * (CB * 36) + rem] =
                    e_ws[((size_t)(o0 + ol) * IN_CH + c0) * 36 + rem];
            }
        }
        __syncthreads();
#pragma unroll 1
        for (int cc = 0; cc < CB; ++cc) {
#pragma unroll
            for (int i = 0; i < 3; ++i) {
#pragma unroll
                for (int j = 0; j < 3; ++j) {
                    float xv0 = sX[cc][qy + i][2 * qxp + j];
                    float xv1 = sX[cc][qy + i][2 * qxp + 1 + j];
#pragma unroll
                    for (int oo = 0; oo < 4; ++oo) {
                        float4 e = sE[((o2 * 4 + oo) * CB + cc) * 9 + i * 3 + j];
                        acc[0][oo].x += xv0 * e.x; acc[0][oo].y += xv0 * e.y;
                        acc[0][oo].z += xv0 * e.z; acc[0][oo].w += xv0 * e.w;
                        acc[1][oo].x += xv1 * e.x; acc[1][oo].y += xv1 * e.y;
                        acc[1][oo].z += xv1 * e.z; acc[1][oo].w += xv1 * e.w;
                    }
                }
            }
        }
        __syncthreads();
    }
#pragma unroll
    for (int q = 0; q < 2; ++q) {
        int qx = 2 * qxp + q;
        int u0 = 2 * (hq0 + qy);
        int v0 = 2 * (wq0 + qx);
#pragma unroll
        for (int oo = 0; oo < 4; ++oo) {
            int o = o0 + o2 * 4 + oo;
            float b = bias[o];
            float vals[4] = {acc[q][oo].x, acc[q][oo].y, acc[q][oo].z, acc[q][oo].w};
#pragma unroll
            for (int p = 0; p < 4; ++p) {
                int pu = p >> 1, pv = p & 1;
                float v = vals[p] + b;
                v = (v >= 0.f ? v : 0.2f * v) * ACT_GAIN;
                v = fminf(fmaxf(v, -CLAMP_V), CLAMP_V);
                out[(((size_t)n * OUT_CH + o) * HOUT + (u0 + pu)) * HOUT + (v0 + pv)] = v;
            }
        }
    }
}

extern "C" void kernel_launch(void* const* d_in, const int* in_sizes, int n_in,
                              void* d_out, int out_size, void* d_ws, size_t ws_size,
                              hipStream_t stream) {
    const float* x = (const float*)d_in[0];
    const float* w = (const float*)d_in[1];
    const float* bias = (const float*)d_in[2];
    float* out = (float*)d_out;

    if (ws_size >= WS_NEED) {
        __hip_bfloat16* xbf = (__hip_bfloat16*)d_ws;
        __hip_bfloat16* ebf = (__hip_bfloat16*)((char*)d_ws + XBF_BYTES);
        xpose_kernel<<<dim3(8, HP, NIMG), 256, 0, stream>>>(x, xbf);
        build_ebf_kernel<<<(OUT_CH * IN_CH + 255) / 256, 256, 0, stream>>>(w, ebf);
        mfma_conv8_kernel<<<dim3(1024), 512, 0, stream>>>(xbf, ebf, bias, out);
    } else {
        float* e_ws = (float*)d_ws;
        build_e_kernel<<<(OUT_CH * IN_CH + 255) / 256, 256, 0, stream>>>(w, e_ws);
        dim3 grid(16, OUT_CH / OGB, NIMG);
        fused_conv_kernel<<<grid, 256, 0, stream>>>(x, e_ws, bias, out);
    }
}